// Round 5
// baseline (747.537 us; speedup 1.0000x reference)
//
#include <hip/hip_runtime.h>
#include <hip/hip_bf16.h>

typedef __hip_bfloat16 bf16;
typedef __bf16 nbf;
typedef nbf bf16x8 __attribute__((ext_vector_type(8)));
typedef float f32x4 __attribute__((ext_vector_type(4)));

#define NNODE 10000
#define DDEG  15
#define EE    320
#define LL    16
#define NH    5
#define HD    64
#define OUTD  30
#define PCOLS 1920   // 6*E : [Qin|Kin|Vin|Qout|Kout|Vout]
#define KF    642    // 2*E + 2 (alpha columns)

// ---------------------------------------------------------------------------
// dtype detection: bf16 data -> low-16 exponent field clustered in [100,140]
// ---------------------------------------------------------------------------
__global__ void detect_dtype_kernel(const unsigned int* __restrict__ X, int* __restrict__ flag)
{
    __shared__ int cnt;
    if (threadIdx.x == 0) cnt = 0;
    __syncthreads();
    int local = 0;
    for (int i = threadIdx.x; i < 1024; i += 256) {
        unsigned int lo = X[i] & 0xFFFFu;
        int e = (int)((lo >> 7) & 0xFFu);
        if (e >= 100 && e <= 140) local++;
    }
    atomicAdd(&cnt, local);
    __syncthreads();
    if (threadIdx.x == 0) *flag = (cnt > 512) ? 1 : 0;
}

__global__ void convert_bf_kernel(const void* __restrict__ src, nbf* __restrict__ dst,
                                  int n, const int* __restrict__ flag)
{
    int i = blockIdx.x * 256 + threadIdx.x;
    if (i >= n) return;
    if (*flag) dst[i] = ((const nbf*)src)[i];
    else       dst[i] = (nbf)(((const float*)src)[i]);
}

#define NSEG 18
struct ConvTab {
    const void* src[NSEG];
    void*       dst[NSEG];
    int         n[NSEG];
    int         tobf[NSEG];
};

__global__ void convert_batch_kernel(ConvTab t, const int* __restrict__ flag)
{
    const int seg = blockIdx.y;
    const int i = blockIdx.x * 256 + threadIdx.x;
    if (i >= t.n[seg]) return;
    float v = (*flag) ? (float)(((const nbf*)t.src[seg])[i]) : ((const float*)t.src[seg])[i];
    if (t.tobf[seg]) ((nbf*)t.dst[seg])[i] = (nbf)v;
    else             ((float*)t.dst[seg])[i] = v;
}

// 3 batched 320x320 transposes: dst[a][e] = src[e][a] (bf16 out)
__global__ __launch_bounds__(256) void transpose3_kernel(const void* s0, const void* s1,
        const void* s2, nbf* __restrict__ dstbase, const int* __restrict__ flag)
{
    const void* src = (blockIdx.z == 0) ? s0 : (blockIdx.z == 1) ? s1 : s2;
    nbf* dst = dstbase + (size_t)blockIdx.z * EE * EE;
    __shared__ nbf tile[32][33];
    const int bx = blockIdx.x * 32, by = blockIdx.y * 32;
    const int tx = threadIdx.x & 31, ty = threadIdx.x >> 5;
    const int f = *flag;
    #pragma unroll
    for (int i = 0; i < 4; ++i) {
        const int r = by + ty + i * 8;
        float v = f ? (float)(((const nbf*)src)[(long)r * EE + bx + tx])
                    : ((const float*)src)[(long)r * EE + bx + tx];
        tile[ty + i * 8][tx] = (nbf)v;
    }
    __syncthreads();
    #pragma unroll
    for (int i = 0; i < 4; ++i) {
        const int r = bx + ty + i * 8;
        dst[(long)r * EE + by + tx] = tile[tx][ty + i * 8];
    }
}

__device__ __forceinline__ void stor(float* p, float v) { *p = v; }
__device__ __forceinline__ void stor(bf16* p, float v) { *p = __float2bfloat16(v); }

// ---------------------------------------------------------------------------
// VALU 64x64 GEMM (tiny compose ops; f32 in)
// ---------------------------------------------------------------------------
template<bool AT, bool BT, typename OT>
__global__ __launch_bounds__(256) void gemm_k(const float* __restrict__ A, int lda,
                       const float* __restrict__ B, int ldb,
                       const float* __restrict__ bias,
                       OT* __restrict__ C, int ldc, int M, int Nn, int K)
{
    __shared__ float As[16][65];
    __shared__ float Bs[16][65];
    const int tid = threadIdx.x;
    const int tx = tid & 15, ty = tid >> 4;
    const int n0 = blockIdx.x * 64, m0 = blockIdx.y * 64;
    float acc[4][4] = {};
    for (int k0 = 0; k0 < K; k0 += 16) {
        if constexpr (AT) {
            for (int i = tid; i < 1024; i += 256) {
                int kk = i >> 6, r = i & 63;
                int gm = m0 + r, gk = k0 + kk;
                As[kk][r] = (gm < M && gk < K) ? A[(long)gk * lda + gm] : 0.f;
            }
        } else {
            for (int i = tid; i < 1024; i += 256) {
                int r = i >> 4, kk = i & 15;
                int gm = m0 + r, gk = k0 + kk;
                As[kk][r] = (gm < M && gk < K) ? A[(long)gm * lda + gk] : 0.f;
            }
        }
        if constexpr (BT) {
            for (int i = tid; i < 1024; i += 256) {
                int r = i >> 4, kk = i & 15;
                int gn = n0 + r, gk = k0 + kk;
                Bs[kk][r] = (gn < Nn && gk < K) ? B[(long)gn * ldb + gk] : 0.f;
            }
        } else {
            for (int i = tid; i < 1024; i += 256) {
                int kk = i >> 6, c = i & 63;
                int gk = k0 + kk, gn = n0 + c;
                Bs[kk][c] = (gk < K && gn < Nn) ? B[(long)gk * ldb + gn] : 0.f;
            }
        }
        __syncthreads();
        #pragma unroll
        for (int kk = 0; kk < 16; ++kk) {
            float ra[4], rb[4];
            #pragma unroll
            for (int a = 0; a < 4; ++a) ra[a] = As[kk][ty * 4 + a];
            #pragma unroll
            for (int b = 0; b < 4; ++b) rb[b] = Bs[kk][tx * 4 + b];
            #pragma unroll
            for (int a = 0; a < 4; ++a)
                #pragma unroll
                for (int b = 0; b < 4; ++b)
                    acc[a][b] += ra[a] * rb[b];
        }
        __syncthreads();
    }
    #pragma unroll
    for (int a = 0; a < 4; ++a) {
        int gm = m0 + ty * 4 + a;
        if (gm >= M) continue;
        #pragma unroll
        for (int b = 0; b < 4; ++b) {
            int gn = n0 + tx * 4 + b;
            if (gn >= Nn) continue;
            float v = acc[a][b] + (bias ? bias[gn] : 0.f);
            stor(&C[(long)gm * ldc + gn], v);
        }
    }
}

// ---------------------------------------------------------------------------
// MFMA bf16 GEMM: C[M,N] = A[M,K] @ Bt[N,K]^T + bias. 128x128 tile, BK=32.
// z-batched via strideA/strideB/strideC (elements).
// ---------------------------------------------------------------------------
template<typename OT>
__global__ __launch_bounds__(256) void gemm_mfma(const nbf* __restrict__ A, int lda,
        const nbf* __restrict__ Bt, int ldb, const float* __restrict__ bias,
        OT* __restrict__ C, int ldc, int M, int Nn, int K,
        long strideA, long strideB, long strideC)
{
    A  += (long)blockIdx.z * strideA;
    Bt += (long)blockIdx.z * strideB;
    C  += (long)blockIdx.z * strideC;
    __shared__ __align__(16) nbf As[128][40];
    __shared__ __align__(16) nbf Bs[128][40];
    const int tid = threadIdx.x;
    const int lane = tid & 63, wave = tid >> 6;
    const int wr = (wave >> 1) * 64, wc = (wave & 1) * 64;
    const int m0 = blockIdx.y * 128, n0 = blockIdx.x * 128;
    const int lr = lane & 15, lq = lane >> 4;
    f32x4 acc[4][4];
    #pragma unroll
    for (int i = 0; i < 4; ++i)
        #pragma unroll
        for (int j = 0; j < 4; ++j) { acc[i][j][0]=0.f; acc[i][j][1]=0.f; acc[i][j][2]=0.f; acc[i][j][3]=0.f; }

    for (int k0 = 0; k0 < K; k0 += 32) {
        #pragma unroll
        for (int v = tid; v < 512; v += 256) {
            const int row = v >> 2, cv = (v & 3) << 3;
            const int gk = k0 + cv;
            {
                const int gm = m0 + row;
                bf16x8 val;
                if (gm < M && gk + 8 <= K) {
                    val = *(const bf16x8*)(A + (long)gm * lda + gk);
                } else {
                    union { bf16x8 v8; nbf e[8]; } u;
                    #pragma unroll
                    for (int j = 0; j < 8; ++j) {
                        float x = (gm < M && gk + j < K) ? (float)A[(long)gm * lda + gk + j] : 0.f;
                        u.e[j] = (nbf)x;
                    }
                    val = u.v8;
                }
                *(bf16x8*)&As[row][cv] = val;
            }
            {
                const int gn = n0 + row;
                bf16x8 val;
                if (gn < Nn && gk + 8 <= K) {
                    val = *(const bf16x8*)(Bt + (long)gn * ldb + gk);
                } else {
                    union { bf16x8 v8; nbf e[8]; } u;
                    #pragma unroll
                    for (int j = 0; j < 8; ++j) {
                        float x = (gn < Nn && gk + j < K) ? (float)Bt[(long)gn * ldb + gk + j] : 0.f;
                        u.e[j] = (nbf)x;
                    }
                    val = u.v8;
                }
                *(bf16x8*)&Bs[row][cv] = val;
            }
        }
        __syncthreads();
        bf16x8 af[4], bfv[4];
        #pragma unroll
        for (int i = 0; i < 4; ++i) af[i] = *(const bf16x8*)&As[wr + i * 16 + lr][lq * 8];
        #pragma unroll
        for (int j = 0; j < 4; ++j) bfv[j] = *(const bf16x8*)&Bs[wc + j * 16 + lr][lq * 8];
        #pragma unroll
        for (int i = 0; i < 4; ++i)
            #pragma unroll
            for (int j = 0; j < 4; ++j)
                acc[i][j] = __builtin_amdgcn_mfma_f32_16x16x32_bf16(af[i], bfv[j], acc[i][j], 0, 0, 0);
        __syncthreads();
    }
    #pragma unroll
    for (int i = 0; i < 4; ++i) {
        #pragma unroll
        for (int j = 0; j < 4; ++j) {
            const int gn = n0 + wc + j * 16 + lr;
            if (gn >= Nn) continue;
            const float bv = bias ? bias[gn] : 0.f;
            #pragma unroll
            for (int r = 0; r < 4; ++r) {
                const int gm = m0 + wr + i * 16 + lq * 4 + r;
                if (gm < M) stor(&C[(long)gm * ldc + gn], acc[i][j][r] + bv);
            }
        }
    }
}

// ---------------------------------------------------------------------------
// which: 0->bqc_in  1->Kcat row640 (bkc_in)  2->Kcat row641 (bkc_out)
//        3->VcatN row640 (bvc_in)            4->VcatN row641 (bvc_out)
// ---------------------------------------------------------------------------
__global__ __launch_bounds__(320) void compose_bias_kernel(
        const float* __restrict__ in_o_b, const float* __restrict__ out_o_b,
        const float* __restrict__ fin_qkv_w, const float* __restrict__ fin_qkv_b,
        float* __restrict__ bqc_in, nbf* __restrict__ Kcat, nbf* __restrict__ VcatN)
{
    const int which = blockIdx.x;
    const int b = threadIdx.x;
    const float* ob = (which == 2 || which == 4) ? out_o_b : in_o_b;
    const int off = (which == 0) ? 0 : (which <= 2) ? 320 : 640;
    float acc = fin_qkv_b[off + b];
    const float* wr = fin_qkv_w + (long)(off + b) * EE;
    for (int e = 0; e < EE; ++e) acc += ob[e] * wr[e];
    if (which == 0)      bqc_in[b] = acc;
    else if (which == 1) Kcat[(long)640 * EE + b] = (nbf)acc;
    else if (which == 2) Kcat[(long)641 * EE + b] = (nbf)acc;
    else if (which == 3) VcatN[(long)640 * EE + b] = (nbf)acc;
    else                 VcatN[(long)641 * EE + b] = (nbf)acc;
}

__global__ void compose_bfin(const float* __restrict__ fin_o_b, const float* __restrict__ W,
                             float* __restrict__ bfin)
{
    int j = threadIdx.x;
    if (j >= OUTD) return;
    float acc = 0.f;
    for (int e = 0; e < EE; ++e) acc += fin_o_b[e] * W[e * OUTD + j];
    bfin[j] = acc;
}

__global__ void compose_bT(const float* __restrict__ bqc, const nbf* __restrict__ Kcat,
                           float* __restrict__ bT)
{
    int c = blockIdx.x * 256 + threadIdx.x;
    if (c >= KF) return;
    const nbf* kr = Kcat + (long)c * EE;
    float acc = 0.f;
    for (int b = 0; b < EE; ++b) acc += bqc[b] * (float)kr[b];
    bT[c] = acc;
}

// ---------------------------------------------------------------------------
// Layer-1 attention, MFMA. Block = 320 threads = 5 waves (1 per head).
// P-scratch overlaid into the wave's own consumed Q column slab -> 31.3 KB LDS
// -> 5 blocks/CU.
// ---------------------------------------------------------------------------
__global__ __launch_bounds__(320) void attn1_kernel(const nbf* __restrict__ P,
                const int* __restrict__ in_idx, const int* __restrict__ out_idx,
                nbf* __restrict__ O, int node_base)
{
    const int bx = blockIdx.x;
    const int lnode = bx >> 1, dir = bx & 1;
    const int node = node_base + lnode;
    const int tid = threadIdx.x;
    const int lane = tid & 63, wave = tid >> 6;      // wave == head
    __shared__ __align__(16) nbf qk_s[16][648];      // [Q 0:320 | K 320:640 | pad]
    __shared__ __align__(16) nbf v_s[16][328];
    __shared__ int srcs[16];
    if (tid < 16) {
        const int* idx = dir ? out_idx : in_idx;
        srcs[tid] = (tid == 0) ? node : idx[node * DDEG + tid - 1];
    }
    __syncthreads();
    const long coloff = (long)dir * 960;
    for (int v = tid; v < 16 * 120; v += 320) {
        const int row = v / 120, c8 = (v % 120) * 8;
        bf16x8 val = *(const bf16x8*)(P + (long)srcs[row] * PCOLS + coloff + c8);
        if (c8 < 640) *(bf16x8*)&qk_s[row][c8] = val;
        else          *(bf16x8*)&v_s[row][c8 - 640] = val;
    }
    __syncthreads();
    const int lr = lane & 15, lq = lane >> 4;
    // ---- QK^T (head = wave), K-dim 64 = 2 MFMA steps ----
    f32x4 sc = {0.f, 0.f, 0.f, 0.f};
    #pragma unroll
    for (int c = 0; c < 2; ++c) {
        bf16x8 aq = *(const bf16x8*)&qk_s[lr][wave * 64 + c * 32 + lq * 8];
        bf16x8 bk = *(const bf16x8*)&qk_s[lr][320 + wave * 64 + c * 32 + lq * 8];
        sc = __builtin_amdgcn_mfma_f32_16x16x32_bf16(aq, bk, sc, 0, 0, 0);
    }
    // ---- softmax over key index m (= lane&15, across 16-lane groups) ----
    float pr[4], mx[4], sm[4];
    #pragma unroll
    for (int r = 0; r < 4; ++r) { pr[r] = sc[r] * 0.125f; mx[r] = pr[r]; }
    #pragma unroll
    for (int msk = 8; msk >= 1; msk >>= 1)
        #pragma unroll
        for (int r = 0; r < 4; ++r) mx[r] = fmaxf(mx[r], __shfl_xor(mx[r], msk));
    #pragma unroll
    for (int r = 0; r < 4; ++r) { pr[r] = __expf(pr[r] - mx[r]); sm[r] = pr[r]; }
    #pragma unroll
    for (int msk = 8; msk >= 1; msk >>= 1)
        #pragma unroll
        for (int r = 0; r < 4; ++r) sm[r] += __shfl_xor(sm[r], msk);
    // P[l=lq*4+r][m=lr] -> overlay into this wave's own Q slab (cols wave*64..+16).
    // Per-wave private: this wave's Q reads already landed in regs (in-order DS).
    #pragma unroll
    for (int r = 0; r < 4; ++r) qk_s[lq * 4 + r][wave * 64 + lr] = (nbf)(pr[r] / sm[r]);
    // B-frag = P^T: lane reads P[n=lr][k=lq*8+j], zeros for k>=16
    union { bf16x8 v8; nbf e[8]; } pf;
    #pragma unroll
    for (int j = 0; j < 8; ++j) pf.e[j] = (nbf)0.f;
    if (lq < 2) pf.v8 = *(const bf16x8*)&qk_s[lr][wave * 64 + lq * 8];
    // ---- O^T[e][l] = sum_m V[m][e] * P[l][m], e in head's 64-col slab ----
    nbf* orow = O + (long)lnode * (32 * EE) + dir * (16 * EE);
    #pragma unroll
    for (int t = 0; t < 4; ++t) {
        const int e0 = wave * 64 + t * 16;
        union { bf16x8 v8; nbf e[8]; } af;
        #pragma unroll
        for (int j = 0; j < 8; ++j) af.e[j] = (nbf)0.f;
        if (lq < 2) {
            #pragma unroll
            for (int j = 0; j < 8; ++j) af.e[j] = v_s[lq * 8 + j][e0 + lr];
        }
        f32x4 ov = {0.f, 0.f, 0.f, 0.f};
        ov = __builtin_amdgcn_mfma_f32_16x16x32_bf16(af.v8, pf.v8, ov, 0, 0, 0);
        union { unsigned long long u; nbf e[4]; } o4;
        #pragma unroll
        for (int r = 0; r < 4; ++r) o4.e[r] = (nbf)ov[r];
        *(unsigned long long*)(orow + lr * EE + e0 + lq * 4) = o4.u;
    }
}

// ---------------------------------------------------------------------------
// Fused final attention + output projection:
// reads O (32 rows) + T row; softmax over 32; G built in LDS; then
// out[i,j] = elu( sum_c G[c] * WWT[j][c] + bfin[j] )  -- WWT = Wfin^T @ Vcat^T
// ---------------------------------------------------------------------------
__global__ __launch_bounds__(256) void final_fused_kernel(const nbf* __restrict__ O,
                const float* __restrict__ T, const float* __restrict__ WWT,
                const float* __restrict__ bfin, void* __restrict__ out,
                long obase, const int* __restrict__ flag)
{
    const int i = blockIdx.x;
    const int tid = threadIdx.x;
    __shared__ __align__(16) nbf o_s[32][328];
    __shared__ float t_s[644];
    __shared__ float g_s[644];
    __shared__ float a_lds[32];
    const nbf* orow = O + (long)i * (32 * EE);
    for (int v = tid; v < 32 * 40; v += 256) {
        const int row = v / 40, cv = (v % 40) * 8;
        *(bf16x8*)&o_s[row][cv] = *(const bf16x8*)(orow + row * EE + cv);
    }
    for (int c = tid; c < KF; c += 256) t_s[c] = T[(long)i * KF + c];
    __syncthreads();
    {
        const int m = tid >> 3, sub = tid & 7;
        const int hoff = (m < 16) ? 0 : 320;
        float p = 0.f;
        #pragma unroll
        for (int jc = 0; jc < 5; ++jc) {
            const int e0 = (jc * 8 + sub) * 8;
            bf16x8 ovv = *(const bf16x8*)&o_s[m][e0];
            #pragma unroll
            for (int j = 0; j < 8; ++j) p += (float)ovv[j] * t_s[hoff + e0 + j];
        }
        p += __shfl_down(p, 4, 8);
        p += __shfl_down(p, 2, 8);
        p += __shfl_down(p, 1, 8);
        if (sub == 0) a_lds[m] = (p + t_s[(m < 16) ? 640 : 641]) * 0.05590169943749474f;
    }
    __syncthreads();
    if (tid < 32) {
        float sv = a_lds[tid];
        float mx = sv;
        for (int o = 16; o > 0; o >>= 1) mx = fmaxf(mx, __shfl_xor(mx, o, 32));
        float e = __expf(sv - mx);
        float sm = e;
        for (int o = 16; o > 0; o >>= 1) sm += __shfl_xor(sm, o, 32);
        a_lds[tid] = e / sm;
    }
    __syncthreads();
    if (tid < 2) {
        float sm = 0.f;
        for (int m = tid * 16; m < tid * 16 + 16; ++m) sm += a_lds[m];
        g_s[640 + tid] = sm;
    }
    for (int v = tid; v < 80; v += 256) {
        const int half = v / 40, cv = (v % 40) * 8;
        float av[8] = {0.f,0.f,0.f,0.f,0.f,0.f,0.f,0.f};
        #pragma unroll
        for (int m = 0; m < 16; ++m) {
            const float a = a_lds[half * 16 + m];
            bf16x8 ovv = *(const bf16x8*)&o_s[half * 16 + m][cv];
            #pragma unroll
            for (int j = 0; j < 8; ++j) av[j] += a * (float)ovv[j];
        }
        #pragma unroll
        for (int j = 0; j < 8; ++j) g_s[half * 320 + cv + j] = av[j];
    }
    __syncthreads();
    // ---- projection: j = tid>>3 (30 outputs), 8 lanes split c ----
    const int j = tid >> 3, sub = tid & 7;
    if (j < OUTD) {
        const float* wr = WWT + (long)j * KF;
        float acc = 0.f;
        for (int c = sub; c < KF; c += 8) acc += g_s[c] * wr[c];
        acc += __shfl_down(acc, 4, 8);
        acc += __shfl_down(acc, 2, 8);
        acc += __shfl_down(acc, 1, 8);
        if (sub == 0) {
            float r = acc + bfin[j];
            r = r > 0.f ? r : expm1f(r);
            if (*flag) ((bf16*)out)[obase + (long)i * OUTD + j] = __float2bfloat16(r);
            else       ((float*)out)[obase + (long)i * OUTD + j] = r;
        }
    }
}

// ---------------------------------------------------------------------------
extern "C" void kernel_launch(void* const* d_in, const int* in_sizes, int n_in,
                              void* d_out, int out_size, void* d_ws, size_t ws_size,
                              hipStream_t stream)
{
    const int* in_idx  = (const int*)d_in[1];
    const int* out_idx = (const int*)d_in[2];

    char* p = (char*)d_ws;
    auto alloc = [&](size_t bytes) { char* r = p; p += (bytes + 255) & ~(size_t)255; return r; };
    const size_t EE2 = (size_t)EE * EE;
    int*   flag       = (int*)alloc(256);
    nbf*   X_bf       = (nbf*)alloc((size_t)NNODE * EE * 2);
    nbf*   qkvw6_bf   = (nbf*)alloc(6 * EE2 * 2);     // [in q,k,v | out q,k,v]
    nbf*   Wg6_bf     = (nbf*)alloc(6 * EE2 * 2);     // in_Wq..out_Wv
    nbf*   qkvw_fin_bf= (nbf*)alloc(3 * EE2 * 2);
    nbf*   owT        = (nbf*)alloc(3 * EE2 * 2);     // [in^T | out^T | fin^T]
    float* qkvw_fin_f = (float*)alloc(3 * EE2 * 4);
    float* qkvb_fin_f = (float*)alloc(3 * EE * 4);
    float* bcat       = (float*)alloc(PCOLS * 4);
    float* ob_in_f    = (float*)alloc(EE * 4);
    float* ob_out_f   = (float*)alloc(EE * 4);
    float* ob_fin_f   = (float*)alloc(EE * 4);
    float* W_f        = (float*)alloc((size_t)EE * OUTD * 4);
    float* ow_fin_f   = (float*)alloc(EE2 * 4);
    // composed
    nbf*   AcatT  = (nbf*)alloc((size_t)PCOLS * EE * 2);   // [1920][320]
    nbf*   Qc_bf  = (nbf*)alloc(EE2 * 2);
    nbf*   Kcat   = (nbf*)alloc((size_t)KF * EE * 2);      // [642][320]
    float* bqc_in = (float*)alloc(EE * 4);
    nbf*   M2T    = (nbf*)alloc((size_t)KF * EE * 2);      // [642][320]
    float* bT     = (float*)alloc(KF * 4);
    nbf*   VcatN  = (nbf*)alloc((size_t)KF * EE * 2);      // [642][320]
    nbf*   WfinT  = (nbf*)alloc((size_t)OUTD * EE * 2);    // [30][320]
    float* WWT    = (float*)alloc((size_t)OUTD * KF * 4);  // [30][642]
    float* bfin   = (float*)alloc(64 * 4);
    nbf*   P      = (nbf*)alloc((size_t)NNODE * PCOLS * 2);
    size_t fixed = (size_t)(p - (char*)d_ws);

    const size_t per_node = (size_t)32 * EE * 2 + (size_t)KF * 4;
    size_t avail = (ws_size > fixed + 65536) ? (ws_size - fixed - 65536) : 0;
    long chunk_l = (long)(avail / (per_node + 8));
    int chunk = (chunk_l > NNODE) ? NNODE : (chunk_l < 1 ? 1 : (int)chunk_l);
    nbf*   O_c    = (nbf*)alloc((size_t)chunk * 32 * EE * 2);
    float* T_c    = (float*)alloc((size_t)chunk * KF * 4);

    dim3 blk(256);
    // ---- detect dtype + normalize inputs ----
    detect_dtype_kernel<<<1, blk, 0, stream>>>((const unsigned int*)d_in[0], flag);
    convert_bf_kernel<<<(NNODE * EE + 255) / 256, blk, 0, stream>>>(d_in[0], X_bf, NNODE * EE, flag);
    ConvTab ct;
    int s = 0;
    auto seg = [&](const void* src, void* dst, int n, int tobf) {
        ct.src[s] = src; ct.dst[s] = dst; ct.n[s] = n; ct.tobf[s] = tobf; ++s;
    };
    seg(d_in[6],  qkvw6_bf,           (int)(3 * EE2), 1);
    seg(d_in[13], qkvw6_bf + 3 * EE2, (int)(3 * EE2), 1);
    seg(d_in[3],  Wg6_bf + 0 * EE2, (int)EE2, 1);
    seg(d_in[4],  Wg6_bf + 1 * EE2, (int)EE2, 1);
    seg(d_in[5],  Wg6_bf + 2 * EE2, (int)EE2, 1);
    seg(d_in[10], Wg6_bf + 3 * EE2, (int)EE2, 1);
    seg(d_in[11], Wg6_bf + 4 * EE2, (int)EE2, 1);
    seg(d_in[12], Wg6_bf + 5 * EE2, (int)EE2, 1);
    seg(d_in[17], qkvw_fin_bf, (int)(3 * EE2), 1);
    seg(d_in[17], qkvw_fin_f,  (int)(3 * EE2), 0);
    seg(d_in[18], qkvb_fin_f, 3 * EE, 0);
    seg(d_in[7],  bcat,       3 * EE, 0);
    seg(d_in[14], bcat + 960, 3 * EE, 0);
    seg(d_in[9],  ob_in_f,  EE, 0);
    seg(d_in[16], ob_out_f, EE, 0);
    seg(d_in[20], ob_fin_f, EE, 0);
    seg(d_in[21], W_f, EE * OUTD, 0);
    seg(d_in[19], ow_fin_f, (int)EE2, 0);
    convert_batch_kernel<<<dim3((3 * (int)EE2 + 255) / 256, NSEG), blk, 0, stream>>>(ct, flag);
    transpose3_kernel<<<dim3(10, 10, 3), blk, 0, stream>>>(d_in[8], d_in[15], d_in[19], owT, flag);

    // ---- compose (all MFMA, bf16) ----
    // AcatT[g] = qkvw6[g] @ Wg6[g]^T   (z-batched)
    gemm_mfma<bf16><<<dim3(3, 3, 6), blk, 0, stream>>>(
        qkvw6_bf, EE, Wg6_bf, EE, nullptr, (bf16*)AcatT, EE, EE, EE, EE,
        (long)EE2, (long)EE2, (long)EE2);
    // Qc = owT_in @ wqf^T
    gemm_mfma<bf16><<<dim3(3, 3, 1), blk, 0, stream>>>(
        owT, EE, qkvw_fin_bf, EE, nullptr, (bf16*)Qc_bf, EE, EE, EE, EE, 0, 0, 0);
    // Kcat rows 0-319 / 320-639 = owT_{in,out} @ wkf^T  (z-batched)
    gemm_mfma<bf16><<<dim3(3, 3, 2), blk, 0, stream>>>(
        owT, EE, qkvw_fin_bf + (size_t)320 * EE, EE, nullptr, (bf16*)Kcat, EE, EE, EE, EE,
        (long)EE2, 0, (long)320 * EE);
    // VcatN rows 0-319 / 320-639 = owT_{in,out} @ wvf^T  (z-batched)
    gemm_mfma<bf16><<<dim3(3, 3, 2), blk, 0, stream>>>(
        owT, EE, qkvw_fin_bf + (size_t)640 * EE, EE, nullptr, (bf16*)VcatN, EE, EE, EE, EE,
        (long)EE2, 0, (long)320 * EE);
    compose_bias_kernel<<<5, 320, 0, stream>>>(ob_in_f, ob_out_f, qkvw_fin_f, qkvb_fin_f,
                                               bqc_in, Kcat, VcatN);
    // M2T = Kcat @ Qc^T
    gemm_mfma<bf16><<<dim3(3, 6, 1), blk, 0, stream>>>(
        Kcat, EE, Qc_bf, EE, nullptr, (bf16*)M2T, EE, KF, EE, EE, 0, 0, 0);
    compose_bT<<<3, blk, 0, stream>>>(bqc_in, Kcat, bT);
    // WfinT[j][e] = sum_a W[a][j] * fin_o_w[a][e]   (VALU, tiny)
    gemm_k<true, false, bf16><<<dim3(5, 1), blk, 0, stream>>>(
        W_f, OUTD, ow_fin_f, EE, nullptr, (bf16*)WfinT, EE, OUTD, EE, EE);
    // WWT[j][c] = sum_e WfinT[j][e] * VcatN[c][e]   (after compose_bias!)
    gemm_mfma<float><<<dim3(6, 1, 1), blk, 0, stream>>>(
        WfinT, EE, VcatN, EE, nullptr, WWT, KF, OUTD, KF, EE, 0, 0, 0);
    compose_bfin<<<1, 64, 0, stream>>>(ob_fin_f, W_f, bfin);

    // ---- P = X @ Acat + bcat  (MFMA) ----
    gemm_mfma<bf16><<<dim3(PCOLS / 128, (NNODE + 127) / 128), blk, 0, stream>>>(
        X_bf, EE, AcatT, EE, bcat, (bf16*)P, PCOLS, NNODE, PCOLS, EE, 0, 0, 0);

    // ---- per-node pipeline (chunked) ----
    for (int base = 0; base < NNODE; base += chunk) {
        int cnt = (NNODE - base < chunk) ? (NNODE - base) : chunk;
        attn1_kernel<<<2 * cnt, dim3(320), 0, stream>>>(P, in_idx, out_idx, O_c, base);
        gemm_mfma<float><<<dim3((KF + 127) / 128, (cnt + 127) / 128), blk, 0, stream>>>(
            O_c, 32 * EE, M2T, EE, bT, T_c, KF, cnt, KF, EE, 0, 0, 0);
        final_fused_kernel<<<cnt, blk, 0, stream>>>(O_c, T_c, WWT, bfin, d_out,
                                                    (long)base * OUTD, flag);
    }
}

// Round 6
// 670.494 us; speedup vs baseline: 1.1149x; 1.1149x over previous
//
#include <hip/hip_runtime.h>
#include <hip/hip_bf16.h>

typedef __hip_bfloat16 bf16;
typedef __bf16 nbf;
typedef nbf bf16x8 __attribute__((ext_vector_type(8)));
typedef float f32x4 __attribute__((ext_vector_type(4)));

#define NNODE 10000
#define DDEG  15
#define EE    320
#define LL    16
#define NH    5
#define HD    64
#define OUTD  30
#define PCOLS 1920   // 6*E : [Qin|Kin|Vin|Qout|Kout|Vout]
#define KF    642    // 2*E + 2 (alpha columns)

// ---------------------------------------------------------------------------
// dtype detection: bf16 data -> low-16 exponent field clustered in [100,140]
// ---------------------------------------------------------------------------
__global__ void detect_dtype_kernel(const unsigned int* __restrict__ X, int* __restrict__ flag)
{
    __shared__ int cnt;
    if (threadIdx.x == 0) cnt = 0;
    __syncthreads();
    int local = 0;
    for (int i = threadIdx.x; i < 1024; i += 256) {
        unsigned int lo = X[i] & 0xFFFFu;
        int e = (int)((lo >> 7) & 0xFFu);
        if (e >= 100 && e <= 140) local++;
    }
    atomicAdd(&cnt, local);
    __syncthreads();
    if (threadIdx.x == 0) *flag = (cnt > 512) ? 1 : 0;
}

__global__ void convert_bf_kernel(const void* __restrict__ src, nbf* __restrict__ dst,
                                  int n, const int* __restrict__ flag)
{
    int i = blockIdx.x * 256 + threadIdx.x;
    if (i >= n) return;
    if (*flag) dst[i] = ((const nbf*)src)[i];
    else       dst[i] = (nbf)(((const float*)src)[i]);
}

#define NSEG 18
struct ConvTab {
    const void* src[NSEG];
    void*       dst[NSEG];
    int         n[NSEG];
    int         tobf[NSEG];
};

__global__ void convert_batch_kernel(ConvTab t, const int* __restrict__ flag)
{
    const int seg = blockIdx.y;
    const int i = blockIdx.x * 256 + threadIdx.x;
    if (i >= t.n[seg]) return;
    float v = (*flag) ? (float)(((const nbf*)t.src[seg])[i]) : ((const float*)t.src[seg])[i];
    if (t.tobf[seg]) ((nbf*)t.dst[seg])[i] = (nbf)v;
    else             ((float*)t.dst[seg])[i] = v;
}

// 3 batched 320x320 transposes: dst[a][e] = src[e][a] (bf16 out)
__global__ __launch_bounds__(256) void transpose3_kernel(const void* s0, const void* s1,
        const void* s2, nbf* __restrict__ dstbase, const int* __restrict__ flag)
{
    const void* src = (blockIdx.z == 0) ? s0 : (blockIdx.z == 1) ? s1 : s2;
    nbf* dst = dstbase + (size_t)blockIdx.z * EE * EE;
    __shared__ nbf tile[32][33];
    const int bx = blockIdx.x * 32, by = blockIdx.y * 32;
    const int tx = threadIdx.x & 31, ty = threadIdx.x >> 5;
    const int f = *flag;
    #pragma unroll
    for (int i = 0; i < 4; ++i) {
        const int r = by + ty + i * 8;
        float v = f ? (float)(((const nbf*)src)[(long)r * EE + bx + tx])
                    : ((const float*)src)[(long)r * EE + bx + tx];
        tile[ty + i * 8][tx] = (nbf)v;
    }
    __syncthreads();
    #pragma unroll
    for (int i = 0; i < 4; ++i) {
        const int r = bx + ty + i * 8;
        dst[(long)r * EE + by + tx] = tile[tx][ty + i * 8];
    }
}

__device__ __forceinline__ void stor(float* p, float v) { *p = v; }
__device__ __forceinline__ void stor(bf16* p, float v) { *p = __float2bfloat16(v); }

// ---------------------------------------------------------------------------
// VALU 64x64 GEMM (tiny compose ops; f32 in)
// ---------------------------------------------------------------------------
template<bool AT, bool BT, typename OT>
__global__ __launch_bounds__(256) void gemm_k(const float* __restrict__ A, int lda,
                       const float* __restrict__ B, int ldb,
                       const float* __restrict__ bias,
                       OT* __restrict__ C, int ldc, int M, int Nn, int K)
{
    __shared__ float As[16][65];
    __shared__ float Bs[16][65];
    const int tid = threadIdx.x;
    const int tx = tid & 15, ty = tid >> 4;
    const int n0 = blockIdx.x * 64, m0 = blockIdx.y * 64;
    float acc[4][4] = {};
    for (int k0 = 0; k0 < K; k0 += 16) {
        if constexpr (AT) {
            for (int i = tid; i < 1024; i += 256) {
                int kk = i >> 6, r = i & 63;
                int gm = m0 + r, gk = k0 + kk;
                As[kk][r] = (gm < M && gk < K) ? A[(long)gk * lda + gm] : 0.f;
            }
        } else {
            for (int i = tid; i < 1024; i += 256) {
                int r = i >> 4, kk = i & 15;
                int gm = m0 + r, gk = k0 + kk;
                As[kk][r] = (gm < M && gk < K) ? A[(long)gm * lda + gk] : 0.f;
            }
        }
        if constexpr (BT) {
            for (int i = tid; i < 1024; i += 256) {
                int r = i >> 4, kk = i & 15;
                int gn = n0 + r, gk = k0 + kk;
                Bs[kk][r] = (gn < Nn && gk < K) ? B[(long)gn * ldb + gk] : 0.f;
            }
        } else {
            for (int i = tid; i < 1024; i += 256) {
                int kk = i >> 6, c = i & 63;
                int gk = k0 + kk, gn = n0 + c;
                Bs[kk][c] = (gk < K && gn < Nn) ? B[(long)gk * ldb + gn] : 0.f;
            }
        }
        __syncthreads();
        #pragma unroll
        for (int kk = 0; kk < 16; ++kk) {
            float ra[4], rb[4];
            #pragma unroll
            for (int a = 0; a < 4; ++a) ra[a] = As[kk][ty * 4 + a];
            #pragma unroll
            for (int b = 0; b < 4; ++b) rb[b] = Bs[kk][tx * 4 + b];
            #pragma unroll
            for (int a = 0; a < 4; ++a)
                #pragma unroll
                for (int b = 0; b < 4; ++b)
                    acc[a][b] += ra[a] * rb[b];
        }
        __syncthreads();
    }
    #pragma unroll
    for (int a = 0; a < 4; ++a) {
        int gm = m0 + ty * 4 + a;
        if (gm >= M) continue;
        #pragma unroll
        for (int b = 0; b < 4; ++b) {
            int gn = n0 + tx * 4 + b;
            if (gn >= Nn) continue;
            float v = acc[a][b] + (bias ? bias[gn] : 0.f);
            stor(&C[(long)gm * ldc + gn], v);
        }
    }
}

// ---------------------------------------------------------------------------
// MFMA bf16 GEMM: C[M,N] = A[M,K] @ Bt[N,K]^T + bias. 128x128 tile, BK=32.
// ---------------------------------------------------------------------------
template<typename OT>
__global__ __launch_bounds__(256) void gemm_mfma(const nbf* __restrict__ A, int lda,
        const nbf* __restrict__ Bt, int ldb, const float* __restrict__ bias,
        OT* __restrict__ C, int ldc, int M, int Nn, int K)
{
    __shared__ __align__(16) nbf As[128][40];
    __shared__ __align__(16) nbf Bs[128][40];
    const int tid = threadIdx.x;
    const int lane = tid & 63, wave = tid >> 6;
    const int wr = (wave >> 1) * 64, wc = (wave & 1) * 64;
    const int m0 = blockIdx.y * 128, n0 = blockIdx.x * 128;
    const int lr = lane & 15, lq = lane >> 4;
    f32x4 acc[4][4];
    #pragma unroll
    for (int i = 0; i < 4; ++i)
        #pragma unroll
        for (int j = 0; j < 4; ++j) { acc[i][j][0]=0.f; acc[i][j][1]=0.f; acc[i][j][2]=0.f; acc[i][j][3]=0.f; }

    for (int k0 = 0; k0 < K; k0 += 32) {
        #pragma unroll
        for (int v = tid; v < 512; v += 256) {
            const int row = v >> 2, cv = (v & 3) << 3;
            const int gk = k0 + cv;
            {
                const int gm = m0 + row;
                bf16x8 val;
                if (gm < M && gk + 8 <= K) {
                    val = *(const bf16x8*)(A + (long)gm * lda + gk);
                } else {
                    union { bf16x8 v8; nbf e[8]; } u;
                    #pragma unroll
                    for (int j = 0; j < 8; ++j) {
                        float x = (gm < M && gk + j < K) ? (float)A[(long)gm * lda + gk + j] : 0.f;
                        u.e[j] = (nbf)x;
                    }
                    val = u.v8;
                }
                *(bf16x8*)&As[row][cv] = val;
            }
            {
                const int gn = n0 + row;
                bf16x8 val;
                if (gn < Nn && gk + 8 <= K) {
                    val = *(const bf16x8*)(Bt + (long)gn * ldb + gk);
                } else {
                    union { bf16x8 v8; nbf e[8]; } u;
                    #pragma unroll
                    for (int j = 0; j < 8; ++j) {
                        float x = (gn < Nn && gk + j < K) ? (float)Bt[(long)gn * ldb + gk + j] : 0.f;
                        u.e[j] = (nbf)x;
                    }
                    val = u.v8;
                }
                *(bf16x8*)&Bs[row][cv] = val;
            }
        }
        __syncthreads();
        bf16x8 af[4], bfv[4];
        #pragma unroll
        for (int i = 0; i < 4; ++i) af[i] = *(const bf16x8*)&As[wr + i * 16 + lr][lq * 8];
        #pragma unroll
        for (int j = 0; j < 4; ++j) bfv[j] = *(const bf16x8*)&Bs[wc + j * 16 + lr][lq * 8];
        #pragma unroll
        for (int i = 0; i < 4; ++i)
            #pragma unroll
            for (int j = 0; j < 4; ++j)
                acc[i][j] = __builtin_amdgcn_mfma_f32_16x16x32_bf16(af[i], bfv[j], acc[i][j], 0, 0, 0);
        __syncthreads();
    }
    #pragma unroll
    for (int i = 0; i < 4; ++i) {
        #pragma unroll
        for (int j = 0; j < 4; ++j) {
            const int gn = n0 + wc + j * 16 + lr;
            if (gn >= Nn) continue;
            const float bv = bias ? bias[gn] : 0.f;
            #pragma unroll
            for (int r = 0; r < 4; ++r) {
                const int gm = m0 + wr + i * 16 + lq * 4 + r;
                if (gm < M) stor(&C[(long)gm * ldc + gn], acc[i][j][r] + bv);
            }
        }
    }
}

// ---------------------------------------------------------------------------
// Batched 320x320x320 bf16 GEMMs (compose stage 1): C[j] = A[j] @ B[j]^T
// grid (3,3,njobs)
// ---------------------------------------------------------------------------
#define NJOB 11
struct JobTab {
    const nbf* A[NJOB];
    const nbf* B[NJOB];
    nbf*       C[NJOB];
};

__global__ __launch_bounds__(256) void gemm_mfma_jobs(JobTab jt)
{
    const nbf* A  = jt.A[blockIdx.z];
    const nbf* Bt = jt.B[blockIdx.z];
    nbf* C        = jt.C[blockIdx.z];
    __shared__ __align__(16) nbf As[128][40];
    __shared__ __align__(16) nbf Bs[128][40];
    const int tid = threadIdx.x;
    const int lane = tid & 63, wave = tid >> 6;
    const int wr = (wave >> 1) * 64, wc = (wave & 1) * 64;
    const int m0 = blockIdx.y * 128, n0 = blockIdx.x * 128;
    const int lr = lane & 15, lq = lane >> 4;
    f32x4 acc[4][4];
    #pragma unroll
    for (int i = 0; i < 4; ++i)
        #pragma unroll
        for (int j = 0; j < 4; ++j) { acc[i][j][0]=0.f; acc[i][j][1]=0.f; acc[i][j][2]=0.f; acc[i][j][3]=0.f; }
    for (int k0 = 0; k0 < EE; k0 += 32) {
        #pragma unroll
        for (int v = tid; v < 512; v += 256) {
            const int row = v >> 2, cv = (v & 3) << 3;
            const int gk = k0 + cv;
            const int gm = m0 + row, gn = n0 + row;
            bf16x8 va = {}, vb = {};
            if (gm < EE) va = *(const bf16x8*)(A + (long)gm * EE + gk);
            if (gn < EE) vb = *(const bf16x8*)(Bt + (long)gn * EE + gk);
            *(bf16x8*)&As[row][cv] = va;
            *(bf16x8*)&Bs[row][cv] = vb;
        }
        __syncthreads();
        bf16x8 af[4], bfv[4];
        #pragma unroll
        for (int i = 0; i < 4; ++i) af[i] = *(const bf16x8*)&As[wr + i * 16 + lr][lq * 8];
        #pragma unroll
        for (int j = 0; j < 4; ++j) bfv[j] = *(const bf16x8*)&Bs[wc + j * 16 + lr][lq * 8];
        #pragma unroll
        for (int i = 0; i < 4; ++i)
            #pragma unroll
            for (int j = 0; j < 4; ++j)
                acc[i][j] = __builtin_amdgcn_mfma_f32_16x16x32_bf16(af[i], bfv[j], acc[i][j], 0, 0, 0);
        __syncthreads();
    }
    #pragma unroll
    for (int i = 0; i < 4; ++i)
        #pragma unroll
        for (int j = 0; j < 4; ++j) {
            const int gn = n0 + wc + j * 16 + lr;
            if (gn >= EE) continue;
            #pragma unroll
            for (int r = 0; r < 4; ++r) {
                const int gm = m0 + wr + i * 16 + lq * 4 + r;
                if (gm < EE) C[(long)gm * EE + gn] = (nbf)acc[i][j][r];
            }
        }
}

// ---------------------------------------------------------------------------
// which: 0->bqc_in  1->Kcat row640  2->Kcat row641  3->VcatN row640  4->row641
// ---------------------------------------------------------------------------
__global__ __launch_bounds__(320) void compose_bias_kernel(
        const float* __restrict__ in_o_b, const float* __restrict__ out_o_b,
        const float* __restrict__ fin_qkv_w, const float* __restrict__ fin_qkv_b,
        float* __restrict__ bqc_in, nbf* __restrict__ Kcat, nbf* __restrict__ VcatN)
{
    const int which = blockIdx.x;
    const int b = threadIdx.x;
    const float* ob = (which == 2 || which == 4) ? out_o_b : in_o_b;
    const int off = (which == 0) ? 0 : (which <= 2) ? 320 : 640;
    float acc = fin_qkv_b[off + b];
    const float* wr = fin_qkv_w + (long)(off + b) * EE;
    for (int e = 0; e < EE; ++e) acc += ob[e] * wr[e];
    if (which == 0)      bqc_in[b] = acc;
    else if (which == 1) Kcat[(long)640 * EE + b] = (nbf)acc;
    else if (which == 2) Kcat[(long)641 * EE + b] = (nbf)acc;
    else if (which == 3) VcatN[(long)640 * EE + b] = (nbf)acc;
    else                 VcatN[(long)641 * EE + b] = (nbf)acc;
}

__global__ void compose_bfin(const float* __restrict__ fin_o_b, const float* __restrict__ W,
                             float* __restrict__ bfin)
{
    int j = threadIdx.x;
    if (j >= OUTD) return;
    float acc = 0.f;
    for (int e = 0; e < EE; ++e) acc += fin_o_b[e] * W[e * OUTD + j];
    bfin[j] = acc;
}

__global__ void compose_bT(const float* __restrict__ bqc, const nbf* __restrict__ Kcat,
                           float* __restrict__ bT)
{
    int c = blockIdx.x * 256 + threadIdx.x;
    if (c >= KF) return;
    const nbf* kr = Kcat + (long)c * EE;
    float acc = 0.f;
    for (int b = 0; b < EE; ++b) acc += bqc[b] * (float)kr[b];
    bT[c] = acc;
}

// Ut[64][320] bf16: rows 0..29 = WWT[:,0:320] (in-proj), 32..61 = WWT[:,320:640]
__global__ void ut_prep_kernel(const float* __restrict__ WWT, nbf* __restrict__ Ut)
{
    int v = blockIdx.x * 256 + threadIdx.x;
    if (v >= 64 * EE) return;
    int n = v / EE, e = v % EE;
    float val = 0.f;
    if (n < OUTD) val = WWT[(long)n * KF + e];
    else if (n >= 32 && n < 32 + OUTD) val = WWT[(long)(n - 32) * KF + 320 + e];
    Ut[v] = (nbf)val;
}

// ---------------------------------------------------------------------------
// Layer-1 attention, MFMA. Block = 320 threads = 5 waves (1 per head).
// O staged through consumed K-slab of LDS -> coalesced vec8 row stores.
// ---------------------------------------------------------------------------
__global__ __launch_bounds__(320) void attn1_kernel(const nbf* __restrict__ P,
                const int* __restrict__ in_idx, const int* __restrict__ out_idx,
                nbf* __restrict__ O, int node_base)
{
    const int bx = blockIdx.x;
    const int lnode = bx >> 1, dir = bx & 1;
    const int node = node_base + lnode;
    const int tid = threadIdx.x;
    const int lane = tid & 63, wave = tid >> 6;      // wave == head
    __shared__ __align__(16) nbf qk_s[16][648];      // [Q 0:320 | K 320:640 | pad]
    __shared__ __align__(16) nbf v_s[16][328];
    __shared__ int srcs[16];
    if (tid < 16) {
        const int* idx = dir ? out_idx : in_idx;
        srcs[tid] = (tid == 0) ? node : idx[node * DDEG + tid - 1];
    }
    __syncthreads();
    const long coloff = (long)dir * 960;
    for (int v = tid; v < 16 * 120; v += 320) {
        const int row = v / 120, c8 = (v % 120) * 8;
        bf16x8 val = *(const bf16x8*)(P + (long)srcs[row] * PCOLS + coloff + c8);
        if (c8 < 640) *(bf16x8*)&qk_s[row][c8] = val;
        else          *(bf16x8*)&v_s[row][c8 - 640] = val;
    }
    __syncthreads();
    const int lr = lane & 15, lq = lane >> 4;
    // ---- QK^T (head = wave), K-dim 64 = 2 MFMA steps ----
    f32x4 sc = {0.f, 0.f, 0.f, 0.f};
    #pragma unroll
    for (int c = 0; c < 2; ++c) {
        bf16x8 aq = *(const bf16x8*)&qk_s[lr][wave * 64 + c * 32 + lq * 8];
        bf16x8 bk = *(const bf16x8*)&qk_s[lr][320 + wave * 64 + c * 32 + lq * 8];
        sc = __builtin_amdgcn_mfma_f32_16x16x32_bf16(aq, bk, sc, 0, 0, 0);
    }
    // ---- softmax over key index m (= lane&15) ----
    float pr[4], mx[4], sm[4];
    #pragma unroll
    for (int r = 0; r < 4; ++r) { pr[r] = sc[r] * 0.125f; mx[r] = pr[r]; }
    #pragma unroll
    for (int msk = 8; msk >= 1; msk >>= 1)
        #pragma unroll
        for (int r = 0; r < 4; ++r) mx[r] = fmaxf(mx[r], __shfl_xor(mx[r], msk));
    #pragma unroll
    for (int r = 0; r < 4; ++r) { pr[r] = __expf(pr[r] - mx[r]); sm[r] = pr[r]; }
    #pragma unroll
    for (int msk = 8; msk >= 1; msk >>= 1)
        #pragma unroll
        for (int r = 0; r < 4; ++r) sm[r] += __shfl_xor(sm[r], msk);
    // P[l][m] -> overlay into this wave's own consumed Q slab
    #pragma unroll
    for (int r = 0; r < 4; ++r) qk_s[lq * 4 + r][wave * 64 + lr] = (nbf)(pr[r] / sm[r]);
    // B-frag = P^T
    union { bf16x8 v8; nbf e[8]; } pf;
    #pragma unroll
    for (int j = 0; j < 8; ++j) pf.e[j] = (nbf)0.f;
    if (lq < 2) pf.v8 = *(const bf16x8*)&qk_s[lr][wave * 64 + lq * 8];
    // ---- O^T = V^T @ P^T, staged into consumed K slab ----
    #pragma unroll
    for (int t = 0; t < 4; ++t) {
        const int e0 = wave * 64 + t * 16;
        union { bf16x8 v8; nbf e[8]; } af;
        #pragma unroll
        for (int j = 0; j < 8; ++j) af.e[j] = (nbf)0.f;
        if (lq < 2) {
            #pragma unroll
            for (int j = 0; j < 8; ++j) af.e[j] = v_s[lq * 8 + j][e0 + lr];
        }
        f32x4 ov = {0.f, 0.f, 0.f, 0.f};
        ov = __builtin_amdgcn_mfma_f32_16x16x32_bf16(af.v8, pf.v8, ov, 0, 0, 0);
        union { unsigned long long u; nbf e[4]; } o4;
        #pragma unroll
        for (int r = 0; r < 4; ++r) o4.e[r] = (nbf)ov[r];
        *(unsigned long long*)&qk_s[lr][320 + e0 + lq * 4] = o4.u;
    }
    __syncthreads();
    // ---- coalesced row store from stage ----
    nbf* orow = O + (long)lnode * (32 * EE) + dir * (16 * EE);
    for (int v = tid; v < 640; v += 320) {
        const int row = v / 40, c8 = (v % 40) * 8;
        *(bf16x8*)(orow + row * EE + c8) = *(const bf16x8*)&qk_s[row][320 + c8];
    }
}

// ---------------------------------------------------------------------------
// Final mega-kernel: 4 nodes/block (wave w = node i0+w). One pass over O:
// D = O_tile @ Ut^T (MFMA, f32 accs in regs), s accumulated in VALU,
// softmax + A-weighted register reduce + alpha terms + ELU + store.
// ---------------------------------------------------------------------------
__global__ __launch_bounds__(256) void final_mega_kernel(const nbf* __restrict__ O,
        const float* __restrict__ T, const nbf* __restrict__ Ut,
        const float* __restrict__ WWT, const float* __restrict__ bfin,
        void* __restrict__ out, long obase, const int* __restrict__ flag)
{
    const int i0 = blockIdx.x * 4;
    const int tid = threadIdx.x;
    const int lane = tid & 63, wave = tid >> 6;
    __shared__ __align__(16) nbf Os[128][40];
    __shared__ __align__(16) nbf Uts[64][40];
    __shared__ float t_s[4][KF];
    __shared__ float s_lds[4][32];
    for (int v = tid; v < 4 * KF; v += 256)
        t_s[v / KF][v % KF] = T[((long)i0 + v / KF) * KF + (v % KF)];
    const int lr = lane & 15, lq = lane >> 4;
    f32x4 acc[2][2];
    #pragma unroll
    for (int a = 0; a < 2; ++a)
        #pragma unroll
        for (int b = 0; b < 2; ++b) { acc[a][b][0]=0.f; acc[a][b][1]=0.f; acc[a][b][2]=0.f; acc[a][b][3]=0.f; }
    float s_acc = 0.f;
    const int srow = lane >> 1, skh = lane & 1;
    const int shoff = (srow < 16) ? 0 : 320;
    for (int k0 = 0; k0 < EE; k0 += 32) {
        __syncthreads();
        #pragma unroll
        for (int v = tid; v < 512; v += 256) {
            const int row = v >> 2, c8 = (v & 3) << 3;
            *(bf16x8*)&Os[row][c8] = *(const bf16x8*)(O + ((long)i0 * 32 + row) * EE + k0 + c8);
        }
        {
            const int row = tid >> 2, c8 = (tid & 3) << 3;
            *(bf16x8*)&Uts[row][c8] = *(const bf16x8*)(Ut + (long)row * EE + k0 + c8);
        }
        __syncthreads();
        bf16x8 af[2], bfv[4];
        #pragma unroll
        for (int mt = 0; mt < 2; ++mt) af[mt] = *(const bf16x8*)&Os[wave * 32 + mt * 16 + lr][lq * 8];
        #pragma unroll
        for (int nt = 0; nt < 4; ++nt) bfv[nt] = *(const bf16x8*)&Uts[nt * 16 + lr][lq * 8];
        #pragma unroll
        for (int mt = 0; mt < 2; ++mt)
            #pragma unroll
            for (int pp = 0; pp < 2; ++pp)
                acc[mt][pp] = __builtin_amdgcn_mfma_f32_16x16x32_bf16(af[mt], bfv[mt * 2 + pp], acc[mt][pp], 0, 0, 0);
        // s partial: lane handles (row = lane>>1, k-half = lane&1)
        const nbf* orow = &Os[wave * 32 + srow][skh * 16];
        const float* trow = &t_s[wave][shoff + k0 + skh * 16];
        #pragma unroll
        for (int k = 0; k < 16; ++k) s_acc += (float)orow[k] * trow[k];
    }
    // finalize s
    s_acc += __shfl_xor(s_acc, 1);
    if (skh == 0)
        s_lds[wave][srow] = (s_acc + t_s[wave][(srow < 16) ? 640 : 641]) * 0.05590169943749474f;
    __syncthreads();
    // softmax per wave (in-lane over 32 values)
    float mx = -1e30f;
    #pragma unroll 4
    for (int m = 0; m < 32; ++m) mx = fmaxf(mx, s_lds[wave][m]);
    float esum = 0.f, a_in = 0.f, a_out = 0.f;
    #pragma unroll 4
    for (int m = 0; m < 32; ++m) {
        float e = __expf(s_lds[wave][m] - mx);
        esum += e;
        if (m < 16) a_in += e; else a_out += e;
    }
    const float inv = 1.f / esum;
    a_in *= inv; a_out *= inv;
    // weighted reduce over this lane's 8 m's
    float pj[2] = {0.f, 0.f};
    #pragma unroll
    for (int r = 0; r < 4; ++r) {
        float A0 = __expf(s_lds[wave][lq * 4 + r] - mx) * inv;
        float A1 = __expf(s_lds[wave][16 + lq * 4 + r] - mx) * inv;
        pj[0] += A0 * acc[0][0][r] + A1 * acc[1][0][r];
        pj[1] += A0 * acc[0][1][r] + A1 * acc[1][1][r];
    }
    #pragma unroll
    for (int pp = 0; pp < 2; ++pp) {
        pj[pp] += __shfl_xor(pj[pp], 16);
        pj[pp] += __shfl_xor(pj[pp], 32);
    }
    if (lq == 0) {
        const long node = i0 + wave;
        #pragma unroll
        for (int h = 0; h < 2; ++h) {
            const int j = h * 16 + lr;
            if (j < OUTD) {
                float r = pj[h] + a_in * WWT[(long)j * KF + 640]
                        + a_out * WWT[(long)j * KF + 641] + bfin[j];
                r = r > 0.f ? r : expm1f(r);
                if (*flag) ((bf16*)out)[obase + node * OUTD + j] = __float2bfloat16(r);
                else       ((float*)out)[obase + node * OUTD + j] = r;
            }
        }
    }
}

// ---------------------------------------------------------------------------
extern "C" void kernel_launch(void* const* d_in, const int* in_sizes, int n_in,
                              void* d_out, int out_size, void* d_ws, size_t ws_size,
                              hipStream_t stream)
{
    const int* in_idx  = (const int*)d_in[1];
    const int* out_idx = (const int*)d_in[2];

    char* p = (char*)d_ws;
    auto alloc = [&](size_t bytes) { char* r = p; p += (bytes + 255) & ~(size_t)255; return r; };
    const size_t EE2 = (size_t)EE * EE;
    int*   flag       = (int*)alloc(256);
    nbf*   X_bf       = (nbf*)alloc((size_t)NNODE * EE * 2);
    nbf*   qkvw6_bf   = (nbf*)alloc(6 * EE2 * 2);     // [in q,k,v | out q,k,v]
    nbf*   Wg6_bf     = (nbf*)alloc(6 * EE2 * 2);     // in_Wq..out_Wv
    nbf*   qkvw_fin_bf= (nbf*)alloc(3 * EE2 * 2);
    nbf*   owT        = (nbf*)alloc(3 * EE2 * 2);     // [in^T | out^T | fin^T]
    float* qkvw_fin_f = (float*)alloc(3 * EE2 * 4);
    float* qkvb_fin_f = (float*)alloc(3 * EE * 4);
    float* bcat       = (float*)alloc(PCOLS * 4);
    float* ob_in_f    = (float*)alloc(EE * 4);
    float* ob_out_f   = (float*)alloc(EE * 4);
    float* ob_fin_f   = (float*)alloc(EE * 4);
    float* W_f        = (float*)alloc((size_t)EE * OUTD * 4);
    float* ow_fin_f   = (float*)alloc(EE2 * 4);
    // composed
    nbf*   AcatT  = (nbf*)alloc((size_t)PCOLS * EE * 2);   // [1920][320]
    nbf*   Qc_bf  = (nbf*)alloc(EE2 * 2);
    nbf*   Kcat   = (nbf*)alloc((size_t)KF * EE * 2);      // [642][320]
    float* bqc_in = (float*)alloc(EE * 4);
    nbf*   M2T    = (nbf*)alloc((size_t)KF * EE * 2);      // [642][320]
    float* bT     = (float*)alloc(KF * 4);
    nbf*   VcatN  = (nbf*)alloc((size_t)KF * EE * 2);      // [642][320]
    nbf*   WfinT  = (nbf*)alloc((size_t)OUTD * EE * 2);    // [30][320]
    float* WWT    = (float*)alloc((size_t)OUTD * KF * 4);  // [30][642]
    float* bfin   = (float*)alloc(64 * 4);
    nbf*   Ut     = (nbf*)alloc((size_t)64 * EE * 2);      // [64][320]
    nbf*   P      = (nbf*)alloc((size_t)NNODE * PCOLS * 2);
    size_t fixed = (size_t)(p - (char*)d_ws);

    const size_t per_node = (size_t)32 * EE * 2 + (size_t)KF * 4;
    size_t avail = (ws_size > fixed + 65536) ? (ws_size - fixed - 65536) : 0;
    long chunk_l = (long)(avail / (per_node + 8));
    chunk_l = (chunk_l / 4) * 4;
    int chunk = (chunk_l > NNODE) ? NNODE : (chunk_l < 4 ? 4 : (int)chunk_l);
    nbf*   O_c    = (nbf*)alloc((size_t)chunk * 32 * EE * 2);
    float* T_c    = (float*)alloc((size_t)chunk * KF * 4);

    dim3 blk(256);
    // ---- detect dtype + normalize inputs ----
    detect_dtype_kernel<<<1, blk, 0, stream>>>((const unsigned int*)d_in[0], flag);
    convert_bf_kernel<<<(NNODE * EE + 255) / 256, blk, 0, stream>>>(d_in[0], X_bf, NNODE * EE, flag);
    ConvTab ct;
    int s = 0;
    auto seg = [&](const void* src, void* dst, int n, int tobf) {
        ct.src[s] = src; ct.dst[s] = dst; ct.n[s] = n; ct.tobf[s] = tobf; ++s;
    };
    seg(d_in[6],  qkvw6_bf,           (int)(3 * EE2), 1);
    seg(d_in[13], qkvw6_bf + 3 * EE2, (int)(3 * EE2), 1);
    seg(d_in[3],  Wg6_bf + 0 * EE2, (int)EE2, 1);
    seg(d_in[4],  Wg6_bf + 1 * EE2, (int)EE2, 1);
    seg(d_in[5],  Wg6_bf + 2 * EE2, (int)EE2, 1);
    seg(d_in[10], Wg6_bf + 3 * EE2, (int)EE2, 1);
    seg(d_in[11], Wg6_bf + 4 * EE2, (int)EE2, 1);
    seg(d_in[12], Wg6_bf + 5 * EE2, (int)EE2, 1);
    seg(d_in[17], qkvw_fin_bf, (int)(3 * EE2), 1);
    seg(d_in[17], qkvw_fin_f,  (int)(3 * EE2), 0);
    seg(d_in[18], qkvb_fin_f, 3 * EE, 0);
    seg(d_in[7],  bcat,       3 * EE, 0);
    seg(d_in[14], bcat + 960, 3 * EE, 0);
    seg(d_in[9],  ob_in_f,  EE, 0);
    seg(d_in[16], ob_out_f, EE, 0);
    seg(d_in[20], ob_fin_f, EE, 0);
    seg(d_in[21], W_f, EE * OUTD, 0);
    seg(d_in[19], ow_fin_f, (int)EE2, 0);
    convert_batch_kernel<<<dim3((3 * (int)EE2 + 255) / 256, NSEG), blk, 0, stream>>>(ct, flag);
    transpose3_kernel<<<dim3(10, 10, 3), blk, 0, stream>>>(d_in[8], d_in[15], d_in[19], owT, flag);

    // ---- compose stage 1: 11 independent 320^3 GEMMs in ONE launch ----
    JobTab jt;
    for (int g = 0; g < 6; ++g) {           // AcatT[g] = qkvw6[g] @ Wg6[g]^T
        jt.A[g] = qkvw6_bf + (size_t)g * EE2;
        jt.B[g] = Wg6_bf + (size_t)g * EE2;
        jt.C[g] = AcatT + (size_t)g * EE2;
    }
    jt.A[6] = owT;             jt.B[6] = qkvw_fin_bf;                      jt.C[6] = Qc_bf;   // Qc
    jt.A[7] = owT;             jt.B[7] = qkvw_fin_bf + (size_t)320 * EE;   jt.C[7] = Kcat;    // Kcat in
    jt.A[8] = owT + EE2;       jt.B[8] = qkvw_fin_bf + (size_t)320 * EE;   jt.C[8] = Kcat + (size_t)320 * EE;
    jt.A[9] = owT;             jt.B[9] = qkvw_fin_bf + (size_t)640 * EE;   jt.C[9] = VcatN;   // VcatN in
    jt.A[10]= owT + EE2;       jt.B[10]= qkvw_fin_bf + (size_t)640 * EE;   jt.C[10]= VcatN + (size_t)320 * EE;
    gemm_mfma_jobs<<<dim3(3, 3, NJOB), blk, 0, stream>>>(jt);
    compose_bias_kernel<<<5, 320, 0, stream>>>(ob_in_f, ob_out_f, qkvw_fin_f, qkvb_fin_f,
                                               bqc_in, Kcat, VcatN);
    // M2T = Kcat @ Qc^T
    gemm_mfma<bf16><<<dim3(3, 6), blk, 0, stream>>>(
        Kcat, EE, Qc_bf, EE, nullptr, (bf16*)M2T, EE, KF, EE, EE);
    compose_bT<<<3, blk, 0, stream>>>(bqc_in, Kcat, bT);
    // WfinT[j][e] = sum_a W[a][j] * fin_o_w[a][e]
    gemm_k<true, false, bf16><<<dim3(5, 1), blk, 0, stream>>>(
        W_f, OUTD, ow_fin_f, EE, nullptr, (bf16*)WfinT, EE, OUTD, EE, EE);
    // WWT[j][c] = sum_e WfinT[j][e] * VcatN[c][e]
    gemm_mfma<float><<<dim3(6, 1), blk, 0, stream>>>(
        WfinT, EE, VcatN, EE, nullptr, WWT, KF, OUTD, KF, EE);
    compose_bfin<<<1, 64, 0, stream>>>(ob_fin_f, W_f, bfin);
    ut_prep_kernel<<<(64 * EE + 255) / 256, blk, 0, stream>>>(WWT, Ut);

    // ---- P = X @ Acat + bcat  (MFMA) ----
    gemm_mfma<bf16><<<dim3(PCOLS / 128, (NNODE + 127) / 128), blk, 0, stream>>>(
        X_bf, EE, AcatT, EE, bcat, (bf16*)P, PCOLS, NNODE, PCOLS, EE);

    // ---- per-node pipeline (chunked) ----
    for (int base = 0; base < NNODE; base += chunk) {
        int cnt = (NNODE - base < chunk) ? (NNODE - base) : chunk;
        attn1_kernel<<<2 * cnt, dim3(320), 0, stream>>>(P, in_idx, out_idx, O_c, base);
        gemm_mfma<float><<<dim3((KF + 127) / 128, (cnt + 127) / 128), blk, 0, stream>>>(
            O_c, 32 * EE, M2T, EE, bT, T_c, KF, cnt, KF, EE);
        final_mega_kernel<<<(cnt + 3) / 4, blk, 0, stream>>>(
            O_c, T_c, Ut, WWT, bfin, d_out, (long)base * OUTD, flag);
    }
}

// Round 7
// 601.521 us; speedup vs baseline: 1.2427x; 1.1147x over previous
//
#include <hip/hip_runtime.h>
#include <hip/hip_bf16.h>

typedef __hip_bfloat16 bf16;
typedef __bf16 nbf;
typedef nbf bf16x8 __attribute__((ext_vector_type(8)));
typedef float f32x4 __attribute__((ext_vector_type(4)));

#define NNODE 10000
#define DDEG  15
#define EE    320
#define LL    16
#define NH    5
#define HD    64
#define OUTD  30
#define PCOLS 1920   // 6*E : [Qin|Kin|Vin|Qout|Kout|Vout]
#define KF    642    // 2*E + 2 (alpha columns)

// ---------------------------------------------------------------------------
// dtype detection: bf16 data -> low-16 exponent field clustered in [100,140]
// ---------------------------------------------------------------------------
__global__ void detect_dtype_kernel(const unsigned int* __restrict__ X, int* __restrict__ flag)
{
    __shared__ int cnt;
    if (threadIdx.x == 0) cnt = 0;
    __syncthreads();
    int local = 0;
    for (int i = threadIdx.x; i < 1024; i += 256) {
        unsigned int lo = X[i] & 0xFFFFu;
        int e = (int)((lo >> 7) & 0xFFu);
        if (e >= 100 && e <= 140) local++;
    }
    atomicAdd(&cnt, local);
    __syncthreads();
    if (threadIdx.x == 0) *flag = (cnt > 512) ? 1 : 0;
}

__global__ void convert_bf_kernel(const void* __restrict__ src, nbf* __restrict__ dst,
                                  int n, const int* __restrict__ flag)
{
    int i = blockIdx.x * 256 + threadIdx.x;
    if (i >= n) return;
    if (*flag) dst[i] = ((const nbf*)src)[i];
    else       dst[i] = (nbf)(((const float*)src)[i]);
}

#define NSEG 18
struct ConvTab {
    const void* src[NSEG];
    void*       dst[NSEG];
    int         n[NSEG];
    int         tobf[NSEG];
};

__global__ void convert_batch_kernel(ConvTab t, const int* __restrict__ flag)
{
    const int seg = blockIdx.y;
    const int i = blockIdx.x * 256 + threadIdx.x;
    if (i >= t.n[seg]) return;
    float v = (*flag) ? (float)(((const nbf*)t.src[seg])[i]) : ((const float*)t.src[seg])[i];
    if (t.tobf[seg]) ((nbf*)t.dst[seg])[i] = (nbf)v;
    else             ((float*)t.dst[seg])[i] = v;
}

// 3 batched 320x320 transposes: dst[a][e] = src[e][a] (bf16 out)
__global__ __launch_bounds__(256) void transpose3_kernel(const void* s0, const void* s1,
        const void* s2, nbf* __restrict__ dstbase, const int* __restrict__ flag)
{
    const void* src = (blockIdx.z == 0) ? s0 : (blockIdx.z == 1) ? s1 : s2;
    nbf* dst = dstbase + (size_t)blockIdx.z * EE * EE;
    __shared__ nbf tile[32][33];
    const int bx = blockIdx.x * 32, by = blockIdx.y * 32;
    const int tx = threadIdx.x & 31, ty = threadIdx.x >> 5;
    const int f = *flag;
    #pragma unroll
    for (int i = 0; i < 4; ++i) {
        const int r = by + ty + i * 8;
        float v = f ? (float)(((const nbf*)src)[(long)r * EE + bx + tx])
                    : ((const float*)src)[(long)r * EE + bx + tx];
        tile[ty + i * 8][tx] = (nbf)v;
    }
    __syncthreads();
    #pragma unroll
    for (int i = 0; i < 4; ++i) {
        const int r = bx + ty + i * 8;
        dst[(long)r * EE + by + tx] = tile[tx][ty + i * 8];
    }
}

__device__ __forceinline__ void stor(float* p, float v) { *p = v; }
__device__ __forceinline__ void stor(bf16* p, float v) { *p = __float2bfloat16(v); }

// ---------------------------------------------------------------------------
// VALU 64x64 GEMM (tiny compose ops; f32 in)
// ---------------------------------------------------------------------------
template<bool AT, bool BT, typename OT>
__global__ __launch_bounds__(256) void gemm_k(const float* __restrict__ A, int lda,
                       const float* __restrict__ B, int ldb,
                       const float* __restrict__ bias,
                       OT* __restrict__ C, int ldc, int M, int Nn, int K)
{
    __shared__ float As[16][65];
    __shared__ float Bs[16][65];
    const int tid = threadIdx.x;
    const int tx = tid & 15, ty = tid >> 4;
    const int n0 = blockIdx.x * 64, m0 = blockIdx.y * 64;
    float acc[4][4] = {};
    for (int k0 = 0; k0 < K; k0 += 16) {
        if constexpr (AT) {
            for (int i = tid; i < 1024; i += 256) {
                int kk = i >> 6, r = i & 63;
                int gm = m0 + r, gk = k0 + kk;
                As[kk][r] = (gm < M && gk < K) ? A[(long)gk * lda + gm] : 0.f;
            }
        } else {
            for (int i = tid; i < 1024; i += 256) {
                int r = i >> 4, kk = i & 15;
                int gm = m0 + r, gk = k0 + kk;
                As[kk][r] = (gm < M && gk < K) ? A[(long)gm * lda + gk] : 0.f;
            }
        }
        if constexpr (BT) {
            for (int i = tid; i < 1024; i += 256) {
                int r = i >> 4, kk = i & 15;
                int gn = n0 + r, gk = k0 + kk;
                Bs[kk][r] = (gn < Nn && gk < K) ? B[(long)gn * ldb + gk] : 0.f;
            }
        } else {
            for (int i = tid; i < 1024; i += 256) {
                int kk = i >> 6, c = i & 63;
                int gk = k0 + kk, gn = n0 + c;
                Bs[kk][c] = (gk < K && gn < Nn) ? B[(long)gk * ldb + gn] : 0.f;
            }
        }
        __syncthreads();
        #pragma unroll
        for (int kk = 0; kk < 16; ++kk) {
            float ra[4], rb[4];
            #pragma unroll
            for (int a = 0; a < 4; ++a) ra[a] = As[kk][ty * 4 + a];
            #pragma unroll
            for (int b = 0; b < 4; ++b) rb[b] = Bs[kk][tx * 4 + b];
            #pragma unroll
            for (int a = 0; a < 4; ++a)
                #pragma unroll
                for (int b = 0; b < 4; ++b)
                    acc[a][b] += ra[a] * rb[b];
        }
        __syncthreads();
    }
    #pragma unroll
    for (int a = 0; a < 4; ++a) {
        int gm = m0 + ty * 4 + a;
        if (gm >= M) continue;
        #pragma unroll
        for (int b = 0; b < 4; ++b) {
            int gn = n0 + tx * 4 + b;
            if (gn >= Nn) continue;
            float v = acc[a][b] + (bias ? bias[gn] : 0.f);
            stor(&C[(long)gm * ldc + gn], v);
        }
    }
}

// ---------------------------------------------------------------------------
// MFMA bf16 GEMM: C[M,N] = A[M,K] @ Bt[N,K]^T + bias. 128x128 tile, BK=32.
// ---------------------------------------------------------------------------
template<typename OT>
__global__ __launch_bounds__(256) void gemm_mfma(const nbf* __restrict__ A, int lda,
        const nbf* __restrict__ Bt, int ldb, const float* __restrict__ bias,
        OT* __restrict__ C, int ldc, int M, int Nn, int K)
{
    __shared__ __align__(16) nbf As[128][40];
    __shared__ __align__(16) nbf Bs[128][40];
    const int tid = threadIdx.x;
    const int lane = tid & 63, wave = tid >> 6;
    const int wr = (wave >> 1) * 64, wc = (wave & 1) * 64;
    const int m0 = blockIdx.y * 128, n0 = blockIdx.x * 128;
    const int lr = lane & 15, lq = lane >> 4;
    f32x4 acc[4][4];
    #pragma unroll
    for (int i = 0; i < 4; ++i)
        #pragma unroll
        for (int j = 0; j < 4; ++j) { acc[i][j][0]=0.f; acc[i][j][1]=0.f; acc[i][j][2]=0.f; acc[i][j][3]=0.f; }

    for (int k0 = 0; k0 < K; k0 += 32) {
        #pragma unroll
        for (int v = tid; v < 512; v += 256) {
            const int row = v >> 2, cv = (v & 3) << 3;
            const int gk = k0 + cv;
            {
                const int gm = m0 + row;
                bf16x8 val;
                if (gm < M && gk + 8 <= K) {
                    val = *(const bf16x8*)(A + (long)gm * lda + gk);
                } else {
                    union { bf16x8 v8; nbf e[8]; } u;
                    #pragma unroll
                    for (int j = 0; j < 8; ++j) {
                        float x = (gm < M && gk + j < K) ? (float)A[(long)gm * lda + gk + j] : 0.f;
                        u.e[j] = (nbf)x;
                    }
                    val = u.v8;
                }
                *(bf16x8*)&As[row][cv] = val;
            }
            {
                const int gn = n0 + row;
                bf16x8 val;
                if (gn < Nn && gk + 8 <= K) {
                    val = *(const bf16x8*)(Bt + (long)gn * ldb + gk);
                } else {
                    union { bf16x8 v8; nbf e[8]; } u;
                    #pragma unroll
                    for (int j = 0; j < 8; ++j) {
                        float x = (gn < Nn && gk + j < K) ? (float)Bt[(long)gn * ldb + gk + j] : 0.f;
                        u.e[j] = (nbf)x;
                    }
                    val = u.v8;
                }
                *(bf16x8*)&Bs[row][cv] = val;
            }
        }
        __syncthreads();
        bf16x8 af[4], bfv[4];
        #pragma unroll
        for (int i = 0; i < 4; ++i) af[i] = *(const bf16x8*)&As[wr + i * 16 + lr][lq * 8];
        #pragma unroll
        for (int j = 0; j < 4; ++j) bfv[j] = *(const bf16x8*)&Bs[wc + j * 16 + lr][lq * 8];
        #pragma unroll
        for (int i = 0; i < 4; ++i)
            #pragma unroll
            for (int j = 0; j < 4; ++j)
                acc[i][j] = __builtin_amdgcn_mfma_f32_16x16x32_bf16(af[i], bfv[j], acc[i][j], 0, 0, 0);
        __syncthreads();
    }
    #pragma unroll
    for (int i = 0; i < 4; ++i) {
        #pragma unroll
        for (int j = 0; j < 4; ++j) {
            const int gn = n0 + wc + j * 16 + lr;
            if (gn >= Nn) continue;
            const float bv = bias ? bias[gn] : 0.f;
            #pragma unroll
            for (int r = 0; r < 4; ++r) {
                const int gm = m0 + wr + i * 16 + lq * 4 + r;
                if (gm < M) stor(&C[(long)gm * ldc + gn], acc[i][j][r] + bv);
            }
        }
    }
}

// ---------------------------------------------------------------------------
// Batched 320x320x320 bf16 GEMMs (compose stage 1): C[j] = A[j] @ B[j]^T
// ---------------------------------------------------------------------------
#define NJOB 11
struct JobTab {
    const nbf* A[NJOB];
    const nbf* B[NJOB];
    nbf*       C[NJOB];
};

__global__ __launch_bounds__(256) void gemm_mfma_jobs(JobTab jt)
{
    const nbf* A  = jt.A[blockIdx.z];
    const nbf* Bt = jt.B[blockIdx.z];
    nbf* C        = jt.C[blockIdx.z];
    __shared__ __align__(16) nbf As[128][40];
    __shared__ __align__(16) nbf Bs[128][40];
    const int tid = threadIdx.x;
    const int lane = tid & 63, wave = tid >> 6;
    const int wr = (wave >> 1) * 64, wc = (wave & 1) * 64;
    const int m0 = blockIdx.y * 128, n0 = blockIdx.x * 128;
    const int lr = lane & 15, lq = lane >> 4;
    f32x4 acc[4][4];
    #pragma unroll
    for (int i = 0; i < 4; ++i)
        #pragma unroll
        for (int j = 0; j < 4; ++j) { acc[i][j][0]=0.f; acc[i][j][1]=0.f; acc[i][j][2]=0.f; acc[i][j][3]=0.f; }
    for (int k0 = 0; k0 < EE; k0 += 32) {
        #pragma unroll
        for (int v = tid; v < 512; v += 256) {
            const int row = v >> 2, cv = (v & 3) << 3;
            const int gk = k0 + cv;
            const int gm = m0 + row, gn = n0 + row;
            bf16x8 va = {}, vb = {};
            if (gm < EE) va = *(const bf16x8*)(A + (long)gm * EE + gk);
            if (gn < EE) vb = *(const bf16x8*)(Bt + (long)gn * EE + gk);
            *(bf16x8*)&As[row][cv] = va;
            *(bf16x8*)&Bs[row][cv] = vb;
        }
        __syncthreads();
        bf16x8 af[4], bfv[4];
        #pragma unroll
        for (int i = 0; i < 4; ++i) af[i] = *(const bf16x8*)&As[wr + i * 16 + lr][lq * 8];
        #pragma unroll
        for (int j = 0; j < 4; ++j) bfv[j] = *(const bf16x8*)&Bs[wc + j * 16 + lr][lq * 8];
        #pragma unroll
        for (int i = 0; i < 4; ++i)
            #pragma unroll
            for (int j = 0; j < 4; ++j)
                acc[i][j] = __builtin_amdgcn_mfma_f32_16x16x32_bf16(af[i], bfv[j], acc[i][j], 0, 0, 0);
        __syncthreads();
    }
    #pragma unroll
    for (int i = 0; i < 4; ++i)
        #pragma unroll
        for (int j = 0; j < 4; ++j) {
            const int gn = n0 + wc + j * 16 + lr;
            if (gn >= EE) continue;
            #pragma unroll
            for (int r = 0; r < 4; ++r) {
                const int gm = m0 + wr + i * 16 + lq * 4 + r;
                if (gm < EE) C[(long)gm * EE + gn] = (nbf)acc[i][j][r];
            }
        }
}

// ---------------------------------------------------------------------------
// which: 0->bqc_in  1->Kcat row640  2->Kcat row641  3->VcatN row640  4->row641
// ---------------------------------------------------------------------------
__global__ __launch_bounds__(320) void compose_bias_kernel(
        const float* __restrict__ in_o_b, const float* __restrict__ out_o_b,
        const float* __restrict__ fin_qkv_w, const float* __restrict__ fin_qkv_b,
        float* __restrict__ bqc_in, nbf* __restrict__ Kcat, nbf* __restrict__ VcatN)
{
    const int which = blockIdx.x;
    const int b = threadIdx.x;
    const float* ob = (which == 2 || which == 4) ? out_o_b : in_o_b;
    const int off = (which == 0) ? 0 : (which <= 2) ? 320 : 640;
    float acc = fin_qkv_b[off + b];
    const float* wr = fin_qkv_w + (long)(off + b) * EE;
    for (int e = 0; e < EE; ++e) acc += ob[e] * wr[e];
    if (which == 0)      bqc_in[b] = acc;
    else if (which == 1) Kcat[(long)640 * EE + b] = (nbf)acc;
    else if (which == 2) Kcat[(long)641 * EE + b] = (nbf)acc;
    else if (which == 3) VcatN[(long)640 * EE + b] = (nbf)acc;
    else                 VcatN[(long)641 * EE + b] = (nbf)acc;
}

__global__ void compose_bfin(const float* __restrict__ fin_o_b, const float* __restrict__ W,
                             float* __restrict__ bfin)
{
    int j = threadIdx.x;
    if (j >= OUTD) return;
    float acc = 0.f;
    for (int e = 0; e < EE; ++e) acc += fin_o_b[e] * W[e * OUTD + j];
    bfin[j] = acc;
}

__global__ void compose_bT(const float* __restrict__ bqc, const nbf* __restrict__ Kcat,
                           float* __restrict__ bT)
{
    int c = blockIdx.x * 256 + threadIdx.x;
    if (c >= KF) return;
    const nbf* kr = Kcat + (long)c * EE;
    float acc = 0.f;
    for (int b = 0; b < EE; ++b) acc += bqc[b] * (float)kr[b];
    bT[c] = acc;
}

// Ut[64][320] bf16: rows 0..29 = WWT[:,0:320] (in-proj), 32..61 = WWT[:,320:640]
__global__ void ut_prep_kernel(const float* __restrict__ WWT, nbf* __restrict__ Ut)
{
    int v = blockIdx.x * 256 + threadIdx.x;
    if (v >= 64 * EE) return;
    int n = v / EE, e = v % EE;
    float val = 0.f;
    if (n < OUTD) val = WWT[(long)n * KF + e];
    else if (n >= 32 && n < 32 + OUTD) val = WWT[(long)(n - 32) * KF + 320 + e];
    Ut[v] = (nbf)val;
}

// ---------------------------------------------------------------------------
// Layer-1 attention, MFMA. Block = 320 threads = 5 waves (1 per head).
// ---------------------------------------------------------------------------
__global__ __launch_bounds__(320) void attn1_kernel(const nbf* __restrict__ P,
                const int* __restrict__ in_idx, const int* __restrict__ out_idx,
                nbf* __restrict__ O, int node_base)
{
    const int bx = blockIdx.x;
    const int lnode = bx >> 1, dir = bx & 1;
    const int node = node_base + lnode;
    const int tid = threadIdx.x;
    const int lane = tid & 63, wave = tid >> 6;      // wave == head
    __shared__ __align__(16) nbf qk_s[16][648];      // [Q 0:320 | K 320:640 | pad]
    __shared__ __align__(16) nbf v_s[16][328];
    __shared__ int srcs[16];
    if (tid < 16) {
        const int* idx = dir ? out_idx : in_idx;
        srcs[tid] = (tid == 0) ? node : idx[node * DDEG + tid - 1];
    }
    __syncthreads();
    const long coloff = (long)dir * 960;
    for (int v = tid; v < 16 * 120; v += 320) {
        const int row = v / 120, c8 = (v % 120) * 8;
        bf16x8 val = *(const bf16x8*)(P + (long)srcs[row] * PCOLS + coloff + c8);
        if (c8 < 640) *(bf16x8*)&qk_s[row][c8] = val;
        else          *(bf16x8*)&v_s[row][c8 - 640] = val;
    }
    __syncthreads();
    const int lr = lane & 15, lq = lane >> 4;
    // ---- QK^T (head = wave), K-dim 64 = 2 MFMA steps ----
    f32x4 sc = {0.f, 0.f, 0.f, 0.f};
    #pragma unroll
    for (int c = 0; c < 2; ++c) {
        bf16x8 aq = *(const bf16x8*)&qk_s[lr][wave * 64 + c * 32 + lq * 8];
        bf16x8 bk = *(const bf16x8*)&qk_s[lr][320 + wave * 64 + c * 32 + lq * 8];
        sc = __builtin_amdgcn_mfma_f32_16x16x32_bf16(aq, bk, sc, 0, 0, 0);
    }
    // ---- softmax over key index m (= lane&15) ----
    float pr[4], mx[4], sm[4];
    #pragma unroll
    for (int r = 0; r < 4; ++r) { pr[r] = sc[r] * 0.125f; mx[r] = pr[r]; }
    #pragma unroll
    for (int msk = 8; msk >= 1; msk >>= 1)
        #pragma unroll
        for (int r = 0; r < 4; ++r) mx[r] = fmaxf(mx[r], __shfl_xor(mx[r], msk));
    #pragma unroll
    for (int r = 0; r < 4; ++r) { pr[r] = __expf(pr[r] - mx[r]); sm[r] = pr[r]; }
    #pragma unroll
    for (int msk = 8; msk >= 1; msk >>= 1)
        #pragma unroll
        for (int r = 0; r < 4; ++r) sm[r] += __shfl_xor(sm[r], msk);
    // P[l][m] -> overlay into this wave's own consumed Q slab
    #pragma unroll
    for (int r = 0; r < 4; ++r) qk_s[lq * 4 + r][wave * 64 + lr] = (nbf)(pr[r] / sm[r]);
    // B-frag = P^T
    union { bf16x8 v8; nbf e[8]; } pf;
    #pragma unroll
    for (int j = 0; j < 8; ++j) pf.e[j] = (nbf)0.f;
    if (lq < 2) pf.v8 = *(const bf16x8*)&qk_s[lr][wave * 64 + lq * 8];
    // ---- O^T = V^T @ P^T, staged into consumed K slab ----
    #pragma unroll
    for (int t = 0; t < 4; ++t) {
        const int e0 = wave * 64 + t * 16;
        union { bf16x8 v8; nbf e[8]; } af;
        #pragma unroll
        for (int j = 0; j < 8; ++j) af.e[j] = (nbf)0.f;
        if (lq < 2) {
            #pragma unroll
            for (int j = 0; j < 8; ++j) af.e[j] = v_s[lq * 8 + j][e0 + lr];
        }
        f32x4 ov = {0.f, 0.f, 0.f, 0.f};
        ov = __builtin_amdgcn_mfma_f32_16x16x32_bf16(af.v8, pf.v8, ov, 0, 0, 0);
        union { unsigned long long u; nbf e[4]; } o4;
        #pragma unroll
        for (int r = 0; r < 4; ++r) o4.e[r] = (nbf)ov[r];
        *(unsigned long long*)&qk_s[lr][320 + e0 + lq * 4] = o4.u;
    }
    __syncthreads();
    // ---- coalesced row store from stage ----
    nbf* orow = O + (long)lnode * (32 * EE) + dir * (16 * EE);
    for (int v = tid; v < 640; v += 320) {
        const int row = v / 40, c8 = (v % 40) * 8;
        *(bf16x8*)(orow + row * EE + c8) = *(const bf16x8*)&qk_s[row][320 + c8];
    }
}

// ---------------------------------------------------------------------------
// Final mega-kernel v3: 4 nodes/block, wave w = node i0+w. Barrier-free K-loop:
// O A-frags and Ut B-frags loaded straight from global into registers
// (Ut is block-invariant -> lives in L2); s-partials computed from the
// register A-frags. Only 2 barriers total (t_s load, s exchange).
// ---------------------------------------------------------------------------
__global__ __launch_bounds__(256) void final_mega_kernel(const nbf* __restrict__ O,
        const float* __restrict__ T, const nbf* __restrict__ Ut,
        const float* __restrict__ WWT, const float* __restrict__ bfin,
        void* __restrict__ out, long obase, int ncnt, const int* __restrict__ flag)
{
    const int i0 = blockIdx.x * 4;
    const int tid = threadIdx.x;
    const int lane = tid & 63, wave = tid >> 6;
    const int node = i0 + wave;
    const int nodec = (node < ncnt) ? node : (ncnt - 1);   // clamp for safe loads
    __shared__ float t_s[4][KF];
    __shared__ float s_lds[4][32];
    for (int v = tid; v < 4 * KF; v += 256) {
        const int nn = v / KF;
        const int nc = (i0 + nn < ncnt) ? (i0 + nn) : (ncnt - 1);
        t_s[nn][v % KF] = T[(long)nc * KF + (v % KF)];
    }
    __syncthreads();
    const int lr = lane & 15, lq = lane >> 4;
    const nbf* obase_p = O + (long)nodec * (32 * EE);
    f32x4 acc[2][2];
    #pragma unroll
    for (int a = 0; a < 2; ++a)
        #pragma unroll
        for (int b = 0; b < 2; ++b) { acc[a][b][0]=0.f; acc[a][b][1]=0.f; acc[a][b][2]=0.f; acc[a][b][3]=0.f; }
    float s_part[2] = {0.f, 0.f};
    #pragma unroll
    for (int k0 = 0; k0 < EE; k0 += 32) {
        bf16x8 af[2], bfv[4];
        #pragma unroll
        for (int mt = 0; mt < 2; ++mt)
            af[mt] = *(const bf16x8*)(obase_p + (long)(mt * 16 + lr) * EE + k0 + lq * 8);
        #pragma unroll
        for (int nt = 0; nt < 4; ++nt)
            bfv[nt] = *(const bf16x8*)(Ut + (long)(nt * 16 + lr) * EE + k0 + lq * 8);
        #pragma unroll
        for (int mt = 0; mt < 2; ++mt)
            #pragma unroll
            for (int pp = 0; pp < 2; ++pp)
                acc[mt][pp] = __builtin_amdgcn_mfma_f32_16x16x32_bf16(af[mt], bfv[mt * 2 + pp], acc[mt][pp], 0, 0, 0);
        // s-partials from the register A-frag: row = mt*16+lr, k = k0+lq*8+j
        #pragma unroll
        for (int mt = 0; mt < 2; ++mt) {
            const float* tp = &t_s[wave][mt * 320 + k0 + lq * 8];
            #pragma unroll
            for (int j = 0; j < 8; ++j) s_part[mt] += (float)af[mt][j] * tp[j];
        }
    }
    // complete s over the 4 lq groups; all lanes end with full dot for row mt*16+lr
    #pragma unroll
    for (int mt = 0; mt < 2; ++mt) {
        s_part[mt] += __shfl_xor(s_part[mt], 16);
        s_part[mt] += __shfl_xor(s_part[mt], 32);
    }
    if (lq == 0) {
        s_lds[wave][lr]      = (s_part[0] + t_s[wave][640]) * 0.05590169943749474f;
        s_lds[wave][16 + lr] = (s_part[1] + t_s[wave][641]) * 0.05590169943749474f;
    }
    __syncthreads();
    // softmax per wave (in-lane over 32 values)
    float mx = -1e30f;
    #pragma unroll 4
    for (int m = 0; m < 32; ++m) mx = fmaxf(mx, s_lds[wave][m]);
    float esum = 0.f, a_in = 0.f, a_out = 0.f;
    #pragma unroll 4
    for (int m = 0; m < 32; ++m) {
        float e = __expf(s_lds[wave][m] - mx);
        esum += e;
        if (m < 16) a_in += e; else a_out += e;
    }
    const float inv = 1.f / esum;
    a_in *= inv; a_out *= inv;
    // weighted reduce over this lane's rows (m = mt*16 + lq*4 + r)
    float pj[2] = {0.f, 0.f};
    #pragma unroll
    for (int r = 0; r < 4; ++r) {
        float A0 = __expf(s_lds[wave][lq * 4 + r] - mx) * inv;
        float A1 = __expf(s_lds[wave][16 + lq * 4 + r] - mx) * inv;
        pj[0] += A0 * acc[0][0][r] + A1 * acc[1][0][r];
        pj[1] += A0 * acc[0][1][r] + A1 * acc[1][1][r];
    }
    #pragma unroll
    for (int pp = 0; pp < 2; ++pp) {
        pj[pp] += __shfl_xor(pj[pp], 16);
        pj[pp] += __shfl_xor(pj[pp], 32);
    }
    if (lq == 0 && node < ncnt) {
        #pragma unroll
        for (int h = 0; h < 2; ++h) {
            const int j = h * 16 + lr;
            if (j < OUTD) {
                float r = pj[h] + a_in * WWT[(long)j * KF + 640]
                        + a_out * WWT[(long)j * KF + 641] + bfin[j];
                r = r > 0.f ? r : expm1f(r);
                if (*flag) ((bf16*)out)[obase + (long)node * OUTD + j] = __float2bfloat16(r);
                else       ((float*)out)[obase + (long)node * OUTD + j] = r;
            }
        }
    }
}

// ---------------------------------------------------------------------------
extern "C" void kernel_launch(void* const* d_in, const int* in_sizes, int n_in,
                              void* d_out, int out_size, void* d_ws, size_t ws_size,
                              hipStream_t stream)
{
    const int* in_idx  = (const int*)d_in[1];
    const int* out_idx = (const int*)d_in[2];

    char* p = (char*)d_ws;
    auto alloc = [&](size_t bytes) { char* r = p; p += (bytes + 255) & ~(size_t)255; return r; };
    const size_t EE2 = (size_t)EE * EE;
    int*   flag       = (int*)alloc(256);
    nbf*   X_bf       = (nbf*)alloc((size_t)NNODE * EE * 2);
    nbf*   qkvw6_bf   = (nbf*)alloc(6 * EE2 * 2);     // [in q,k,v | out q,k,v]
    nbf*   Wg6_bf     = (nbf*)alloc(6 * EE2 * 2);     // in_Wq..out_Wv
    nbf*   qkvw_fin_bf= (nbf*)alloc(3 * EE2 * 2);
    nbf*   owT        = (nbf*)alloc(3 * EE2 * 2);     // [in^T | out^T | fin^T]
    float* qkvw_fin_f = (float*)alloc(3 * EE2 * 4);
    float* qkvb_fin_f = (float*)alloc(3 * EE * 4);
    float* bcat       = (float*)alloc(PCOLS * 4);
    float* ob_in_f    = (float*)alloc(EE * 4);
    float* ob_out_f   = (float*)alloc(EE * 4);
    float* ob_fin_f   = (float*)alloc(EE * 4);
    float* W_f        = (float*)alloc((size_t)EE * OUTD * 4);
    float* ow_fin_f   = (float*)alloc(EE2 * 4);
    // composed
    nbf*   AcatT  = (nbf*)alloc((size_t)PCOLS * EE * 2);   // [1920][320]
    nbf*   Qc_bf  = (nbf*)alloc(EE2 * 2);
    nbf*   Kcat   = (nbf*)alloc((size_t)KF * EE * 2);      // [642][320]
    float* bqc_in = (float*)alloc(EE * 4);
    nbf*   M2T    = (nbf*)alloc((size_t)KF * EE * 2);      // [642][320]
    float* bT     = (float*)alloc(KF * 4);
    nbf*   VcatN  = (nbf*)alloc((size_t)KF * EE * 2);      // [642][320]
    nbf*   WfinT  = (nbf*)alloc((size_t)OUTD * EE * 2);    // [30][320]
    float* WWT    = (float*)alloc((size_t)OUTD * KF * 4);  // [30][642]
    float* bfin   = (float*)alloc(64 * 4);
    nbf*   Ut     = (nbf*)alloc((size_t)64 * EE * 2);      // [64][320]
    nbf*   P      = (nbf*)alloc((size_t)NNODE * PCOLS * 2);
    size_t fixed = (size_t)(p - (char*)d_ws);

    const size_t per_node = (size_t)32 * EE * 2 + (size_t)KF * 4;
    size_t avail = (ws_size > fixed + 65536) ? (ws_size - fixed - 65536) : 0;
    long chunk_l = (long)(avail / (per_node + 8));
    chunk_l = (chunk_l / 4) * 4;
    int chunk = (chunk_l > NNODE) ? NNODE : (chunk_l < 4 ? 4 : (int)chunk_l);
    nbf*   O_c    = (nbf*)alloc((size_t)chunk * 32 * EE * 2);
    float* T_c    = (float*)alloc((size_t)chunk * KF * 4);

    dim3 blk(256);
    // ---- detect dtype + normalize inputs ----
    detect_dtype_kernel<<<1, blk, 0, stream>>>((const unsigned int*)d_in[0], flag);
    convert_bf_kernel<<<(NNODE * EE + 255) / 256, blk, 0, stream>>>(d_in[0], X_bf, NNODE * EE, flag);
    ConvTab ct;
    int s = 0;
    auto seg = [&](const void* src, void* dst, int n, int tobf) {
        ct.src[s] = src; ct.dst[s] = dst; ct.n[s] = n; ct.tobf[s] = tobf; ++s;
    };
    seg(d_in[6],  qkvw6_bf,           (int)(3 * EE2), 1);
    seg(d_in[13], qkvw6_bf + 3 * EE2, (int)(3 * EE2), 1);
    seg(d_in[3],  Wg6_bf + 0 * EE2, (int)EE2, 1);
    seg(d_in[4],  Wg6_bf + 1 * EE2, (int)EE2, 1);
    seg(d_in[5],  Wg6_bf + 2 * EE2, (int)EE2, 1);
    seg(d_in[10], Wg6_bf + 3 * EE2, (int)EE2, 1);
    seg(d_in[11], Wg6_bf + 4 * EE2, (int)EE2, 1);
    seg(d_in[12], Wg6_bf + 5 * EE2, (int)EE2, 1);
    seg(d_in[17], qkvw_fin_bf, (int)(3 * EE2), 1);
    seg(d_in[17], qkvw_fin_f,  (int)(3 * EE2), 0);
    seg(d_in[18], qkvb_fin_f, 3 * EE, 0);
    seg(d_in[7],  bcat,       3 * EE, 0);
    seg(d_in[14], bcat + 960, 3 * EE, 0);
    seg(d_in[9],  ob_in_f,  EE, 0);
    seg(d_in[16], ob_out_f, EE, 0);
    seg(d_in[20], ob_fin_f, EE, 0);
    seg(d_in[21], W_f, EE * OUTD, 0);
    seg(d_in[19], ow_fin_f, (int)EE2, 0);
    convert_batch_kernel<<<dim3((3 * (int)EE2 + 255) / 256, NSEG), blk, 0, stream>>>(ct, flag);
    transpose3_kernel<<<dim3(10, 10, 3), blk, 0, stream>>>(d_in[8], d_in[15], d_in[19], owT, flag);

    // ---- compose stage 1: 11 independent 320^3 GEMMs in ONE launch ----
    JobTab jt;
    for (int g = 0; g < 6; ++g) {           // AcatT[g] = qkvw6[g] @ Wg6[g]^T
        jt.A[g] = qkvw6_bf + (size_t)g * EE2;
        jt.B[g] = Wg6_bf + (size_t)g * EE2;
        jt.C[g] = AcatT + (size_t)g * EE2;
    }
    jt.A[6] = owT;             jt.B[6] = qkvw_fin_bf;                      jt.C[6] = Qc_bf;   // Qc
    jt.A[7] = owT;             jt.B[7] = qkvw_fin_bf + (size_t)320 * EE;   jt.C[7] = Kcat;    // Kcat in
    jt.A[8] = owT + EE2;       jt.B[8] = qkvw_fin_bf + (size_t)320 * EE;   jt.C[8] = Kcat + (size_t)320 * EE;
    jt.A[9] = owT;             jt.B[9] = qkvw_fin_bf + (size_t)640 * EE;   jt.C[9] = VcatN;   // VcatN in
    jt.A[10]= owT + EE2;       jt.B[10]= qkvw_fin_bf + (size_t)640 * EE;   jt.C[10]= VcatN + (size_t)320 * EE;
    gemm_mfma_jobs<<<dim3(3, 3, NJOB), blk, 0, stream>>>(jt);
    compose_bias_kernel<<<5, 320, 0, stream>>>(ob_in_f, ob_out_f, qkvw_fin_f, qkvb_fin_f,
                                               bqc_in, Kcat, VcatN);
    // M2T = Kcat @ Qc^T
    gemm_mfma<bf16><<<dim3(3, 6), blk, 0, stream>>>(
        Kcat, EE, Qc_bf, EE, nullptr, (bf16*)M2T, EE, KF, EE, EE);
    compose_bT<<<3, blk, 0, stream>>>(bqc_in, Kcat, bT);
    // WfinT[j][e] = sum_a W[a][j] * fin_o_w[a][e]
    gemm_k<true, false, bf16><<<dim3(5, 1), blk, 0, stream>>>(
        W_f, OUTD, ow_fin_f, EE, nullptr, (bf16*)WfinT, EE, OUTD, EE, EE);
    // WWT[j][c] = sum_e WfinT[j][e] * VcatN[c][e]
    gemm_mfma<float><<<dim3(6, 1), blk, 0, stream>>>(
        WfinT, EE, VcatN, EE, nullptr, WWT, KF, OUTD, KF, EE);
    compose_bfin<<<1, 64, 0, stream>>>(ob_fin_f, W_f, bfin);
    ut_prep_kernel<<<(64 * EE + 255) / 256, blk, 0, stream>>>(WWT, Ut);

    // ---- P = X @ Acat + bcat  (MFMA) ----
    gemm_mfma<bf16><<<dim3(PCOLS / 128, (NNODE + 127) / 128), blk, 0, stream>>>(
        X_bf, EE, AcatT, EE, bcat, (bf16*)P, PCOLS, NNODE, PCOLS, EE);

    // ---- per-node pipeline (chunked) ----
    for (int base = 0; base < NNODE; base += chunk) {
        int cnt = (NNODE - base < chunk) ? (NNODE - base) : chunk;
        attn1_kernel<<<2 * cnt, dim3(320), 0, stream>>>(P, in_idx, out_idx, O_c, base);
        gemm_mfma<float><<<dim3((KF + 127) / 128, (cnt + 127) / 128), blk, 0, stream>>>(
            O_c, 32 * EE, M2T, EE, bT, T_c, KF, cnt, KF, EE);
        final_mega_kernel<<<(cnt + 3) / 4, blk, 0, stream>>>(
            O_c, T_c, Ut, WWT, bfin, d_out, (long)base * OUTD, cnt, flag);
    }
}

// Round 8
// 587.668 us; speedup vs baseline: 1.2720x; 1.0236x over previous
//
#include <hip/hip_runtime.h>
#include <hip/hip_bf16.h>

typedef __hip_bfloat16 bf16;
typedef __bf16 nbf;
typedef nbf bf16x8 __attribute__((ext_vector_type(8)));
typedef float f32x4 __attribute__((ext_vector_type(4)));

#define NNODE 10000
#define DDEG  15
#define EE    320
#define LL    16
#define NH    5
#define HD    64
#define OUTD  30
#define PCOLS 1920   // 6*E : [Qin|Kin|Vin|Qout|Kout|Vout]
#define KF    642    // 2*E + 2 (alpha columns)

// ---------------------------------------------------------------------------
// dtype detection: bf16 data -> low-16 exponent field clustered in [100,140]
// ---------------------------------------------------------------------------
__global__ void detect_dtype_kernel(const unsigned int* __restrict__ X, int* __restrict__ flag)
{
    __shared__ int cnt;
    if (threadIdx.x == 0) cnt = 0;
    __syncthreads();
    int local = 0;
    for (int i = threadIdx.x; i < 1024; i += 256) {
        unsigned int lo = X[i] & 0xFFFFu;
        int e = (int)((lo >> 7) & 0xFFu);
        if (e >= 100 && e <= 140) local++;
    }
    atomicAdd(&cnt, local);
    __syncthreads();
    if (threadIdx.x == 0) *flag = (cnt > 512) ? 1 : 0;
}

__global__ void convert_bf_kernel(const void* __restrict__ src, nbf* __restrict__ dst,
                                  int n, const int* __restrict__ flag)
{
    int i = blockIdx.x * 256 + threadIdx.x;
    if (i >= n) return;
    if (*flag) dst[i] = ((const nbf*)src)[i];
    else       dst[i] = (nbf)(((const float*)src)[i]);
}

#define NSEG 18
struct ConvTab {
    const void* src[NSEG];
    void*       dst[NSEG];
    int         n[NSEG];
    int         tobf[NSEG];
};

__global__ void convert_batch_kernel(ConvTab t, const int* __restrict__ flag)
{
    const int seg = blockIdx.y;
    const int i = blockIdx.x * 256 + threadIdx.x;
    if (i >= t.n[seg]) return;
    float v = (*flag) ? (float)(((const nbf*)t.src[seg])[i]) : ((const float*)t.src[seg])[i];
    if (t.tobf[seg]) ((nbf*)t.dst[seg])[i] = (nbf)v;
    else             ((float*)t.dst[seg])[i] = v;
}

// 3 batched 320x320 transposes: dst[a][e] = src[e][a] (bf16 out)
__global__ __launch_bounds__(256) void transpose3_kernel(const void* s0, const void* s1,
        const void* s2, nbf* __restrict__ dstbase, const int* __restrict__ flag)
{
    const void* src = (blockIdx.z == 0) ? s0 : (blockIdx.z == 1) ? s1 : s2;
    nbf* dst = dstbase + (size_t)blockIdx.z * EE * EE;
    __shared__ nbf tile[32][33];
    const int bx = blockIdx.x * 32, by = blockIdx.y * 32;
    const int tx = threadIdx.x & 31, ty = threadIdx.x >> 5;
    const int f = *flag;
    #pragma unroll
    for (int i = 0; i < 4; ++i) {
        const int r = by + ty + i * 8;
        float v = f ? (float)(((const nbf*)src)[(long)r * EE + bx + tx])
                    : ((const float*)src)[(long)r * EE + bx + tx];
        tile[ty + i * 8][tx] = (nbf)v;
    }
    __syncthreads();
    #pragma unroll
    for (int i = 0; i < 4; ++i) {
        const int r = bx + ty + i * 8;
        dst[(long)r * EE + by + tx] = tile[tx][ty + i * 8];
    }
}

__device__ __forceinline__ void stor(float* p, float v) { *p = v; }
__device__ __forceinline__ void stor(bf16* p, float v) { *p = __float2bfloat16(v); }

// ---------------------------------------------------------------------------
// VALU 64x64 GEMM (tiny compose ops; f32 in)
// ---------------------------------------------------------------------------
template<bool AT, bool BT, typename OT>
__global__ __launch_bounds__(256) void gemm_k(const float* __restrict__ A, int lda,
                       const float* __restrict__ B, int ldb,
                       const float* __restrict__ bias,
                       OT* __restrict__ C, int ldc, int M, int Nn, int K)
{
    __shared__ float As[16][65];
    __shared__ float Bs[16][65];
    const int tid = threadIdx.x;
    const int tx = tid & 15, ty = tid >> 4;
    const int n0 = blockIdx.x * 64, m0 = blockIdx.y * 64;
    float acc[4][4] = {};
    for (int k0 = 0; k0 < K; k0 += 16) {
        if constexpr (AT) {
            for (int i = tid; i < 1024; i += 256) {
                int kk = i >> 6, r = i & 63;
                int gm = m0 + r, gk = k0 + kk;
                As[kk][r] = (gm < M && gk < K) ? A[(long)gk * lda + gm] : 0.f;
            }
        } else {
            for (int i = tid; i < 1024; i += 256) {
                int r = i >> 4, kk = i & 15;
                int gm = m0 + r, gk = k0 + kk;
                As[kk][r] = (gm < M && gk < K) ? A[(long)gm * lda + gk] : 0.f;
            }
        }
        if constexpr (BT) {
            for (int i = tid; i < 1024; i += 256) {
                int r = i >> 4, kk = i & 15;
                int gn = n0 + r, gk = k0 + kk;
                Bs[kk][r] = (gn < Nn && gk < K) ? B[(long)gn * ldb + gk] : 0.f;
            }
        } else {
            for (int i = tid; i < 1024; i += 256) {
                int kk = i >> 6, c = i & 63;
                int gk = k0 + kk, gn = n0 + c;
                Bs[kk][c] = (gk < K && gn < Nn) ? B[(long)gk * ldb + gn] : 0.f;
            }
        }
        __syncthreads();
        #pragma unroll
        for (int kk = 0; kk < 16; ++kk) {
            float ra[4], rb[4];
            #pragma unroll
            for (int a = 0; a < 4; ++a) ra[a] = As[kk][ty * 4 + a];
            #pragma unroll
            for (int b = 0; b < 4; ++b) rb[b] = Bs[kk][tx * 4 + b];
            #pragma unroll
            for (int a = 0; a < 4; ++a)
                #pragma unroll
                for (int b = 0; b < 4; ++b)
                    acc[a][b] += ra[a] * rb[b];
        }
        __syncthreads();
    }
    #pragma unroll
    for (int a = 0; a < 4; ++a) {
        int gm = m0 + ty * 4 + a;
        if (gm >= M) continue;
        #pragma unroll
        for (int b = 0; b < 4; ++b) {
            int gn = n0 + tx * 4 + b;
            if (gn >= Nn) continue;
            float v = acc[a][b] + (bias ? bias[gn] : 0.f);
            stor(&C[(long)gm * ldc + gn], v);
        }
    }
}

// ---------------------------------------------------------------------------
// MFMA bf16 GEMM: C[M,N] = A[M,K] @ Bt[N,K]^T + bias. 128x128 tile, BK=32.
// ---------------------------------------------------------------------------
template<typename OT>
__global__ __launch_bounds__(256) void gemm_mfma(const nbf* __restrict__ A, int lda,
        const nbf* __restrict__ Bt, int ldb, const float* __restrict__ bias,
        OT* __restrict__ C, int ldc, int M, int Nn, int K)
{
    __shared__ __align__(16) nbf As[128][40];
    __shared__ __align__(16) nbf Bs[128][40];
    const int tid = threadIdx.x;
    const int lane = tid & 63, wave = tid >> 6;
    const int wr = (wave >> 1) * 64, wc = (wave & 1) * 64;
    const int m0 = blockIdx.y * 128, n0 = blockIdx.x * 128;
    const int lr = lane & 15, lq = lane >> 4;
    f32x4 acc[4][4];
    #pragma unroll
    for (int i = 0; i < 4; ++i)
        #pragma unroll
        for (int j = 0; j < 4; ++j) { acc[i][j][0]=0.f; acc[i][j][1]=0.f; acc[i][j][2]=0.f; acc[i][j][3]=0.f; }

    for (int k0 = 0; k0 < K; k0 += 32) {
        #pragma unroll
        for (int v = tid; v < 512; v += 256) {
            const int row = v >> 2, cv = (v & 3) << 3;
            const int gk = k0 + cv;
            {
                const int gm = m0 + row;
                bf16x8 val;
                if (gm < M && gk + 8 <= K) {
                    val = *(const bf16x8*)(A + (long)gm * lda + gk);
                } else {
                    union { bf16x8 v8; nbf e[8]; } u;
                    #pragma unroll
                    for (int j = 0; j < 8; ++j) {
                        float x = (gm < M && gk + j < K) ? (float)A[(long)gm * lda + gk + j] : 0.f;
                        u.e[j] = (nbf)x;
                    }
                    val = u.v8;
                }
                *(bf16x8*)&As[row][cv] = val;
            }
            {
                const int gn = n0 + row;
                bf16x8 val;
                if (gn < Nn && gk + 8 <= K) {
                    val = *(const bf16x8*)(Bt + (long)gn * ldb + gk);
                } else {
                    union { bf16x8 v8; nbf e[8]; } u;
                    #pragma unroll
                    for (int j = 0; j < 8; ++j) {
                        float x = (gn < Nn && gk + j < K) ? (float)Bt[(long)gn * ldb + gk + j] : 0.f;
                        u.e[j] = (nbf)x;
                    }
                    val = u.v8;
                }
                *(bf16x8*)&Bs[row][cv] = val;
            }
        }
        __syncthreads();
        bf16x8 af[4], bfv[4];
        #pragma unroll
        for (int i = 0; i < 4; ++i) af[i] = *(const bf16x8*)&As[wr + i * 16 + lr][lq * 8];
        #pragma unroll
        for (int j = 0; j < 4; ++j) bfv[j] = *(const bf16x8*)&Bs[wc + j * 16 + lr][lq * 8];
        #pragma unroll
        for (int i = 0; i < 4; ++i)
            #pragma unroll
            for (int j = 0; j < 4; ++j)
                acc[i][j] = __builtin_amdgcn_mfma_f32_16x16x32_bf16(af[i], bfv[j], acc[i][j], 0, 0, 0);
        __syncthreads();
    }
    #pragma unroll
    for (int i = 0; i < 4; ++i) {
        #pragma unroll
        for (int j = 0; j < 4; ++j) {
            const int gn = n0 + wc + j * 16 + lr;
            if (gn >= Nn) continue;
            const float bv = bias ? bias[gn] : 0.f;
            #pragma unroll
            for (int r = 0; r < 4; ++r) {
                const int gm = m0 + wr + i * 16 + lq * 4 + r;
                if (gm < M) stor(&C[(long)gm * ldc + gn], acc[i][j][r] + bv);
            }
        }
    }
}

// ---------------------------------------------------------------------------
// Batched 320x320x320 bf16 GEMMs (compose stage 1): C[j] = A[j] @ B[j]^T
// ---------------------------------------------------------------------------
#define NJOB 11
struct JobTab {
    const nbf* A[NJOB];
    const nbf* B[NJOB];
    nbf*       C[NJOB];
};

__global__ __launch_bounds__(256) void gemm_mfma_jobs(JobTab jt)
{
    const nbf* A  = jt.A[blockIdx.z];
    const nbf* Bt = jt.B[blockIdx.z];
    nbf* C        = jt.C[blockIdx.z];
    __shared__ __align__(16) nbf As[128][40];
    __shared__ __align__(16) nbf Bs[128][40];
    const int tid = threadIdx.x;
    const int lane = tid & 63, wave = tid >> 6;
    const int wr = (wave >> 1) * 64, wc = (wave & 1) * 64;
    const int m0 = blockIdx.y * 128, n0 = blockIdx.x * 128;
    const int lr = lane & 15, lq = lane >> 4;
    f32x4 acc[4][4];
    #pragma unroll
    for (int i = 0; i < 4; ++i)
        #pragma unroll
        for (int j = 0; j < 4; ++j) { acc[i][j][0]=0.f; acc[i][j][1]=0.f; acc[i][j][2]=0.f; acc[i][j][3]=0.f; }
    for (int k0 = 0; k0 < EE; k0 += 32) {
        #pragma unroll
        for (int v = tid; v < 512; v += 256) {
            const int row = v >> 2, cv = (v & 3) << 3;
            const int gk = k0 + cv;
            const int gm = m0 + row, gn = n0 + row;
            bf16x8 va = {}, vb = {};
            if (gm < EE) va = *(const bf16x8*)(A + (long)gm * EE + gk);
            if (gn < EE) vb = *(const bf16x8*)(Bt + (long)gn * EE + gk);
            *(bf16x8*)&As[row][cv] = va;
            *(bf16x8*)&Bs[row][cv] = vb;
        }
        __syncthreads();
        bf16x8 af[4], bfv[4];
        #pragma unroll
        for (int i = 0; i < 4; ++i) af[i] = *(const bf16x8*)&As[wr + i * 16 + lr][lq * 8];
        #pragma unroll
        for (int j = 0; j < 4; ++j) bfv[j] = *(const bf16x8*)&Bs[wc + j * 16 + lr][lq * 8];
        #pragma unroll
        for (int i = 0; i < 4; ++i)
            #pragma unroll
            for (int j = 0; j < 4; ++j)
                acc[i][j] = __builtin_amdgcn_mfma_f32_16x16x32_bf16(af[i], bfv[j], acc[i][j], 0, 0, 0);
        __syncthreads();
    }
    #pragma unroll
    for (int i = 0; i < 4; ++i)
        #pragma unroll
        for (int j = 0; j < 4; ++j) {
            const int gn = n0 + wc + j * 16 + lr;
            if (gn >= EE) continue;
            #pragma unroll
            for (int r = 0; r < 4; ++r) {
                const int gm = m0 + wr + i * 16 + lq * 4 + r;
                if (gm < EE) C[(long)gm * EE + gn] = (nbf)acc[i][j][r];
            }
        }
}

// ---------------------------------------------------------------------------
// which: 0->bqc_in  1->Kcat row640  2->Kcat row641  3->VcatN row640  4->row641
// ---------------------------------------------------------------------------
__global__ __launch_bounds__(320) void compose_bias_kernel(
        const float* __restrict__ in_o_b, const float* __restrict__ out_o_b,
        const float* __restrict__ fin_qkv_w, const float* __restrict__ fin_qkv_b,
        float* __restrict__ bqc_in, nbf* __restrict__ Kcat, nbf* __restrict__ VcatN)
{
    const int which = blockIdx.x;
    const int b = threadIdx.x;
    const float* ob = (which == 2 || which == 4) ? out_o_b : in_o_b;
    const int off = (which == 0) ? 0 : (which <= 2) ? 320 : 640;
    float acc = fin_qkv_b[off + b];
    const float* wr = fin_qkv_w + (long)(off + b) * EE;
    for (int e = 0; e < EE; ++e) acc += ob[e] * wr[e];
    if (which == 0)      bqc_in[b] = acc;
    else if (which == 1) Kcat[(long)640 * EE + b] = (nbf)acc;
    else if (which == 2) Kcat[(long)641 * EE + b] = (nbf)acc;
    else if (which == 3) VcatN[(long)640 * EE + b] = (nbf)acc;
    else                 VcatN[(long)641 * EE + b] = (nbf)acc;
}

__global__ void compose_bfin(const float* __restrict__ fin_o_b, const float* __restrict__ W,
                             float* __restrict__ bfin)
{
    int j = threadIdx.x;
    if (j >= OUTD) return;
    float acc = 0.f;
    for (int e = 0; e < EE; ++e) acc += fin_o_b[e] * W[e * OUTD + j];
    bfin[j] = acc;
}

__global__ void compose_bT(const float* __restrict__ bqc, const nbf* __restrict__ Kcat,
                           float* __restrict__ bT)
{
    int c = blockIdx.x * 256 + threadIdx.x;
    if (c >= KF) return;
    const nbf* kr = Kcat + (long)c * EE;
    float acc = 0.f;
    for (int b = 0; b < EE; ++b) acc += bqc[b] * (float)kr[b];
    bT[c] = acc;
}

// Ut[64][320] bf16: rows 0..29 = WWT[:,0:320] (in-proj), 32..61 = WWT[:,320:640]
__global__ void ut_prep_kernel(const float* __restrict__ WWT, nbf* __restrict__ Ut)
{
    int v = blockIdx.x * 256 + threadIdx.x;
    if (v >= 64 * EE) return;
    int n = v / EE, e = v % EE;
    float val = 0.f;
    if (n < OUTD) val = WWT[(long)n * KF + e];
    else if (n >= 32 && n < 32 + OUTD) val = WWT[(long)(n - 32) * KF + 320 + e];
    Ut[v] = (nbf)val;
}

// ---------------------------------------------------------------------------
// Layer-1 attention v4: minimal LDS (V + P-matrix only, ~13 KB), 1 barrier.
// Q/K MFMA fragments loaded DIRECTLY from global (each 16B consumed by
// exactly one lane); per-lane src from idx (no shared srcs array).
// ---------------------------------------------------------------------------
__global__ __launch_bounds__(320) void attn1_kernel(const nbf* __restrict__ P,
                const int* __restrict__ in_idx, const int* __restrict__ out_idx,
                nbf* __restrict__ O, int node_base)
{
    const int bx = blockIdx.x;
    const int lnode = bx >> 1, dir = bx & 1;
    const int node = node_base + lnode;
    const int tid = threadIdx.x;
    const int lane = tid & 63, wave = tid >> 6;      // wave == head
    __shared__ __align__(16) nbf v_s[16][328];
    __shared__ __align__(16) nbf p_s[NH][16][16];
    const int* idx = dir ? out_idx : in_idx;
    const long coloff = (long)dir * 960;
    const int lr = lane & 15, lq = lane >> 4;
    // ---- stage V (only), srcs computed inline ----
    #pragma unroll
    for (int v = tid; v < 640; v += 320) {
        const int row = v / 40, c8 = (v % 40) * 8;
        const int src = (row == 0) ? node : idx[node * DDEG + row - 1];
        *(bf16x8*)&v_s[row][c8] = *(const bf16x8*)(P + (long)src * PCOLS + coloff + 640 + c8);
    }
    // ---- Q/K fragments direct from global; QK^T overlaps V staging ----
    const int msrc = (lr == 0) ? node : idx[node * DDEG + lr - 1];
    const nbf* prow = P + (long)msrc * PCOLS + coloff;
    f32x4 sc = {0.f, 0.f, 0.f, 0.f};
    #pragma unroll
    for (int c = 0; c < 2; ++c) {
        bf16x8 aq = *(const bf16x8*)(prow + wave * 64 + c * 32 + lq * 8);
        bf16x8 bk = *(const bf16x8*)(prow + 320 + wave * 64 + c * 32 + lq * 8);
        sc = __builtin_amdgcn_mfma_f32_16x16x32_bf16(aq, bk, sc, 0, 0, 0);
    }
    // ---- softmax over key index m (= lane&15) ----
    float pr[4], mx[4], sm[4];
    #pragma unroll
    for (int r = 0; r < 4; ++r) { pr[r] = sc[r] * 0.125f; mx[r] = pr[r]; }
    #pragma unroll
    for (int msk = 8; msk >= 1; msk >>= 1)
        #pragma unroll
        for (int r = 0; r < 4; ++r) mx[r] = fmaxf(mx[r], __shfl_xor(mx[r], msk));
    #pragma unroll
    for (int r = 0; r < 4; ++r) { pr[r] = __expf(pr[r] - mx[r]); sm[r] = pr[r]; }
    #pragma unroll
    for (int msk = 8; msk >= 1; msk >>= 1)
        #pragma unroll
        for (int r = 0; r < 4; ++r) sm[r] += __shfl_xor(sm[r], msk);
    // P[l=lq*4+r][m=lr] -> wave-private LDS (no barrier: same-wave DS ordering)
    #pragma unroll
    for (int r = 0; r < 4; ++r) p_s[wave][lq * 4 + r][lr] = (nbf)(pr[r] / sm[r]);
    // B-frag = P^T: lane reads p_s[wave][n=lr][k=lq*8+j], zeros for k>=16
    union { bf16x8 v8; nbf e[8]; } pf;
    #pragma unroll
    for (int j = 0; j < 8; ++j) pf.e[j] = (nbf)0.f;
    if (lq < 2) pf.v8 = *(const bf16x8*)&p_s[wave][lr][lq * 8];
    __syncthreads();   // v_s ready
    // ---- O^T = V^T @ P^T, direct 8B stores ----
    nbf* orow = O + (long)lnode * (32 * EE) + dir * (16 * EE);
    #pragma unroll
    for (int t = 0; t < 4; ++t) {
        const int e0 = wave * 64 + t * 16;
        union { bf16x8 v8; nbf e[8]; } af;
        #pragma unroll
        for (int j = 0; j < 8; ++j) af.e[j] = (nbf)0.f;
        if (lq < 2) {
            #pragma unroll
            for (int j = 0; j < 8; ++j) af.e[j] = v_s[lq * 8 + j][e0 + lr];
        }
        f32x4 ov = {0.f, 0.f, 0.f, 0.f};
        ov = __builtin_amdgcn_mfma_f32_16x16x32_bf16(af.v8, pf.v8, ov, 0, 0, 0);
        union { unsigned long long u; nbf e[4]; } o4;
        #pragma unroll
        for (int r = 0; r < 4; ++r) o4.e[r] = (nbf)ov[r];
        *(unsigned long long*)(orow + lr * EE + e0 + lq * 4) = o4.u;
    }
}

// ---------------------------------------------------------------------------
// Final mega-kernel v3: 4 nodes/block, wave w = node i0+w. Barrier-free K-loop.
// ---------------------------------------------------------------------------
__global__ __launch_bounds__(256) void final_mega_kernel(const nbf* __restrict__ O,
        const float* __restrict__ T, const nbf* __restrict__ Ut,
        const float* __restrict__ WWT, const float* __restrict__ bfin,
        void* __restrict__ out, long obase, int ncnt, const int* __restrict__ flag)
{
    const int i0 = blockIdx.x * 4;
    const int tid = threadIdx.x;
    const int lane = tid & 63, wave = tid >> 6;
    const int node = i0 + wave;
    const int nodec = (node < ncnt) ? node : (ncnt - 1);   // clamp for safe loads
    __shared__ float t_s[4][KF];
    __shared__ float s_lds[4][32];
    for (int v = tid; v < 4 * KF; v += 256) {
        const int nn = v / KF;
        const int nc = (i0 + nn < ncnt) ? (i0 + nn) : (ncnt - 1);
        t_s[nn][v % KF] = T[(long)nc * KF + (v % KF)];
    }
    __syncthreads();
    const int lr = lane & 15, lq = lane >> 4;
    const nbf* obase_p = O + (long)nodec * (32 * EE);
    f32x4 acc[2][2];
    #pragma unroll
    for (int a = 0; a < 2; ++a)
        #pragma unroll
        for (int b = 0; b < 2; ++b) { acc[a][b][0]=0.f; acc[a][b][1]=0.f; acc[a][b][2]=0.f; acc[a][b][3]=0.f; }
    float s_part[2] = {0.f, 0.f};
    #pragma unroll
    for (int k0 = 0; k0 < EE; k0 += 32) {
        bf16x8 af[2], bfv[4];
        #pragma unroll
        for (int mt = 0; mt < 2; ++mt)
            af[mt] = *(const bf16x8*)(obase_p + (long)(mt * 16 + lr) * EE + k0 + lq * 8);
        #pragma unroll
        for (int nt = 0; nt < 4; ++nt)
            bfv[nt] = *(const bf16x8*)(Ut + (long)(nt * 16 + lr) * EE + k0 + lq * 8);
        #pragma unroll
        for (int mt = 0; mt < 2; ++mt)
            #pragma unroll
            for (int pp = 0; pp < 2; ++pp)
                acc[mt][pp] = __builtin_amdgcn_mfma_f32_16x16x32_bf16(af[mt], bfv[mt * 2 + pp], acc[mt][pp], 0, 0, 0);
        #pragma unroll
        for (int mt = 0; mt < 2; ++mt) {
            const float* tp = &t_s[wave][mt * 320 + k0 + lq * 8];
            #pragma unroll
            for (int j = 0; j < 8; ++j) s_part[mt] += (float)af[mt][j] * tp[j];
        }
    }
    #pragma unroll
    for (int mt = 0; mt < 2; ++mt) {
        s_part[mt] += __shfl_xor(s_part[mt], 16);
        s_part[mt] += __shfl_xor(s_part[mt], 32);
    }
    if (lq == 0) {
        s_lds[wave][lr]      = (s_part[0] + t_s[wave][640]) * 0.05590169943749474f;
        s_lds[wave][16 + lr] = (s_part[1] + t_s[wave][641]) * 0.05590169943749474f;
    }
    __syncthreads();
    float mx = -1e30f;
    #pragma unroll 4
    for (int m = 0; m < 32; ++m) mx = fmaxf(mx, s_lds[wave][m]);
    float esum = 0.f, a_in = 0.f, a_out = 0.f;
    #pragma unroll 4
    for (int m = 0; m < 32; ++m) {
        float e = __expf(s_lds[wave][m] - mx);
        esum += e;
        if (m < 16) a_in += e; else a_out += e;
    }
    const float inv = 1.f / esum;
    a_in *= inv; a_out *= inv;
    float pj[2] = {0.f, 0.f};
    #pragma unroll
    for (int r = 0; r < 4; ++r) {
        float A0 = __expf(s_lds[wave][lq * 4 + r] - mx) * inv;
        float A1 = __expf(s_lds[wave][16 + lq * 4 + r] - mx) * inv;
        pj[0] += A0 * acc[0][0][r] + A1 * acc[1][0][r];
        pj[1] += A0 * acc[0][1][r] + A1 * acc[1][1][r];
    }
    #pragma unroll
    for (int pp = 0; pp < 2; ++pp) {
        pj[pp] += __shfl_xor(pj[pp], 16);
        pj[pp] += __shfl_xor(pj[pp], 32);
    }
    if (lq == 0 && node < ncnt) {
        #pragma unroll
        for (int h = 0; h < 2; ++h) {
            const int j = h * 16 + lr;
            if (j < OUTD) {
                float r = pj[h] + a_in * WWT[(long)j * KF + 640]
                        + a_out * WWT[(long)j * KF + 641] + bfin[j];
                r = r > 0.f ? r : expm1f(r);
                if (*flag) ((bf16*)out)[obase + (long)node * OUTD + j] = __float2bfloat16(r);
                else       ((float*)out)[obase + (long)node * OUTD + j] = r;
            }
        }
    }
}

// ---------------------------------------------------------------------------
extern "C" void kernel_launch(void* const* d_in, const int* in_sizes, int n_in,
                              void* d_out, int out_size, void* d_ws, size_t ws_size,
                              hipStream_t stream)
{
    const int* in_idx  = (const int*)d_in[1];
    const int* out_idx = (const int*)d_in[2];

    char* p = (char*)d_ws;
    auto alloc = [&](size_t bytes) { char* r = p; p += (bytes + 255) & ~(size_t)255; return r; };
    const size_t EE2 = (size_t)EE * EE;
    int*   flag       = (int*)alloc(256);
    nbf*   X_bf       = (nbf*)alloc((size_t)NNODE * EE * 2);
    nbf*   qkvw6_bf   = (nbf*)alloc(6 * EE2 * 2);     // [in q,k,v | out q,k,v]
    nbf*   Wg6_bf     = (nbf*)alloc(6 * EE2 * 2);     // in_Wq..out_Wv
    nbf*   qkvw_fin_bf= (nbf*)alloc(3 * EE2 * 2);
    nbf*   owT        = (nbf*)alloc(3 * EE2 * 2);     // [in^T | out^T | fin^T]
    float* qkvw_fin_f = (float*)alloc(3 * EE2 * 4);
    float* qkvb_fin_f = (float*)alloc(3 * EE * 4);
    float* bcat       = (float*)alloc(PCOLS * 4);
    float* ob_in_f    = (float*)alloc(EE * 4);
    float* ob_out_f   = (float*)alloc(EE * 4);
    float* ob_fin_f   = (float*)alloc(EE * 4);
    float* W_f        = (float*)alloc((size_t)EE * OUTD * 4);
    float* ow_fin_f   = (float*)alloc(EE2 * 4);
    // composed
    nbf*   AcatT  = (nbf*)alloc((size_t)PCOLS * EE * 2);   // [1920][320]
    nbf*   Qc_bf  = (nbf*)alloc(EE2 * 2);
    nbf*   Kcat   = (nbf*)alloc((size_t)KF * EE * 2);      // [642][320]
    float* bqc_in = (float*)alloc(EE * 4);
    nbf*   M2T    = (nbf*)alloc((size_t)KF * EE * 2);      // [642][320]
    float* bT     = (float*)alloc(KF * 4);
    nbf*   VcatN  = (nbf*)alloc((size_t)KF * EE * 2);      // [642][320]
    nbf*   WfinT  = (nbf*)alloc((size_t)OUTD * EE * 2);    // [30][320]
    float* WWT    = (float*)alloc((size_t)OUTD * KF * 4);  // [30][642]
    float* bfin   = (float*)alloc(64 * 4);
    nbf*   Ut     = (nbf*)alloc((size_t)64 * EE * 2);      // [64][320]
    nbf*   P      = (nbf*)alloc((size_t)NNODE * PCOLS * 2);
    size_t fixed = (size_t)(p - (char*)d_ws);

    const size_t per_node = (size_t)32 * EE * 2 + (size_t)KF * 4;
    size_t avail = (ws_size > fixed + 65536) ? (ws_size - fixed - 65536) : 0;
    long chunk_l = (long)(avail / (per_node + 8));
    chunk_l = (chunk_l / 4) * 4;
    int chunk = (chunk_l > NNODE) ? NNODE : (chunk_l < 4 ? 4 : (int)chunk_l);
    nbf*   O_c    = (nbf*)alloc((size_t)chunk * 32 * EE * 2);
    float* T_c    = (float*)alloc((size_t)chunk * KF * 4);

    dim3 blk(256);
    // ---- detect dtype + normalize inputs ----
    detect_dtype_kernel<<<1, blk, 0, stream>>>((const unsigned int*)d_in[0], flag);
    convert_bf_kernel<<<(NNODE * EE + 255) / 256, blk, 0, stream>>>(d_in[0], X_bf, NNODE * EE, flag);
    ConvTab ct;
    int s = 0;
    auto seg = [&](const void* src, void* dst, int n, int tobf) {
        ct.src[s] = src; ct.dst[s] = dst; ct.n[s] = n; ct.tobf[s] = tobf; ++s;
    };
    seg(d_in[6],  qkvw6_bf,           (int)(3 * EE2), 1);
    seg(d_in[13], qkvw6_bf + 3 * EE2, (int)(3 * EE2), 1);
    seg(d_in[3],  Wg6_bf + 0 * EE2, (int)EE2, 1);
    seg(d_in[4],  Wg6_bf + 1 * EE2, (int)EE2, 1);
    seg(d_in[5],  Wg6_bf + 2 * EE2, (int)EE2, 1);
    seg(d_in[10], Wg6_bf + 3 * EE2, (int)EE2, 1);
    seg(d_in[11], Wg6_bf + 4 * EE2, (int)EE2, 1);
    seg(d_in[12], Wg6_bf + 5 * EE2, (int)EE2, 1);
    seg(d_in[17], qkvw_fin_bf, (int)(3 * EE2), 1);
    seg(d_in[17], qkvw_fin_f,  (int)(3 * EE2), 0);
    seg(d_in[18], qkvb_fin_f, 3 * EE, 0);
    seg(d_in[7],  bcat,       3 * EE, 0);
    seg(d_in[14], bcat + 960, 3 * EE, 0);
    seg(d_in[9],  ob_in_f,  EE, 0);
    seg(d_in[16], ob_out_f, EE, 0);
    seg(d_in[20], ob_fin_f, EE, 0);
    seg(d_in[21], W_f, EE * OUTD, 0);
    seg(d_in[19], ow_fin_f, (int)EE2, 0);
    convert_batch_kernel<<<dim3((3 * (int)EE2 + 255) / 256, NSEG), blk, 0, stream>>>(ct, flag);
    transpose3_kernel<<<dim3(10, 10, 3), blk, 0, stream>>>(d_in[8], d_in[15], d_in[19], owT, flag);

    // ---- compose stage 1: 11 independent 320^3 GEMMs in ONE launch ----
    JobTab jt;
    for (int g = 0; g < 6; ++g) {           // AcatT[g] = qkvw6[g] @ Wg6[g]^T
        jt.A[g] = qkvw6_bf + (size_t)g * EE2;
        jt.B[g] = Wg6_bf + (size_t)g * EE2;
        jt.C[g] = AcatT + (size_t)g * EE2;
    }
    jt.A[6] = owT;             jt.B[6] = qkvw_fin_bf;                      jt.C[6] = Qc_bf;   // Qc
    jt.A[7] = owT;             jt.B[7] = qkvw_fin_bf + (size_t)320 * EE;   jt.C[7] = Kcat;    // Kcat in
    jt.A[8] = owT + EE2;       jt.B[8] = qkvw_fin_bf + (size_t)320 * EE;   jt.C[8] = Kcat + (size_t)320 * EE;
    jt.A[9] = owT;             jt.B[9] = qkvw_fin_bf + (size_t)640 * EE;   jt.C[9] = VcatN;   // VcatN in
    jt.A[10]= owT + EE2;       jt.B[10]= qkvw_fin_bf + (size_t)640 * EE;   jt.C[10]= VcatN + (size_t)320 * EE;
    gemm_mfma_jobs<<<dim3(3, 3, NJOB), blk, 0, stream>>>(jt);
    compose_bias_kernel<<<5, 320, 0, stream>>>(ob_in_f, ob_out_f, qkvw_fin_f, qkvb_fin_f,
                                               bqc_in, Kcat, VcatN);
    // M2T = Kcat @ Qc^T
    gemm_mfma<bf16><<<dim3(3, 6), blk, 0, stream>>>(
        Kcat, EE, Qc_bf, EE, nullptr, (bf16*)M2T, EE, KF, EE, EE);
    compose_bT<<<3, blk, 0, stream>>>(bqc_in, Kcat, bT);
    // WfinT[j][e] = sum_a W[a][j] * fin_o_w[a][e]
    gemm_k<true, false, bf16><<<dim3(5, 1), blk, 0, stream>>>(
        W_f, OUTD, ow_fin_f, EE, nullptr, (bf16*)WfinT, EE, OUTD, EE, EE);
    // WWT[j][c] = sum_e WfinT[j][e] * VcatN[c][e]
    gemm_mfma<float><<<dim3(6, 1), blk, 0, stream>>>(
        WfinT, EE, VcatN, EE, nullptr, WWT, KF, OUTD, KF, EE);
    compose_bfin<<<1, 64, 0, stream>>>(ob_fin_f, W_f, bfin);
    ut_prep_kernel<<<(64 * EE + 255) / 256, blk, 0, stream>>>(WWT, Ut);

    // ---- P = X @ Acat + bcat  (MFMA) ----
    gemm_mfma<bf16><<<dim3(PCOLS / 128, (NNODE + 127) / 128), blk, 0, stream>>>(
        X_bf, EE, AcatT, EE, bcat, (bf16*)P, PCOLS, NNODE, PCOLS, EE);

    // ---- per-node pipeline (chunked) ----
    for (int base = 0; base < NNODE; base += chunk) {
        int cnt = (NNODE - base < chunk) ? (NNODE - base) : chunk;
        attn1_kernel<<<2 * cnt, dim3(320), 0, stream>>>(P, in_idx, out_idx, O_c, base);
        gemm_mfma<float><<<dim3((KF + 127) / 128, (cnt + 127) / 128), blk, 0, stream>>>(
            O_c, 32 * EE, M2T, EE, bT, T_c, KF, cnt, KF, EE);
        final_mega_kernel<<<(cnt + 3) / 4, blk, 0, stream>>>(
            O_c, T_c, Ut, WWT, bfin, d_out, (long)base * OUTD, cnt, flag);
    }
}